// Round 1
// 429.820 us; speedup vs baseline: 1.0097x; 1.0097x over previous
//
#include <hip/hip_runtime.h>
#include <math.h>

#define NB 2
#define NL 1024
#define ND 1024
#define NH 2048
#define NE 8
#define NTOK (NB*NL)      // 2048 tokens; per-expert slot capacity = NTOK
#define NSLOT (NTOK*2)

typedef float f32x4 __attribute__((ext_vector_type(4)));
typedef short s16x8 __attribute__((ext_vector_type(8)));
typedef short s16x4 __attribute__((ext_vector_type(4)));
typedef unsigned u32x4 __attribute__((ext_vector_type(4)));

__device__ __forceinline__ unsigned short f2bf(float f) {
    union { float f; unsigned u; } v; v.f = f;
    unsigned r = v.u + 0x7FFFu + ((v.u >> 16) & 1u);
    return (unsigned short)(r >> 16);
}

// packed fp32->bf16 RNE convert (2 elems / inst); matches f2bf rounding
__device__ __forceinline__ unsigned pk2(float a, float b) {
    unsigned r;
    asm("v_cvt_pk_bf16_f32 %0, %1, %2" : "=v"(r) : "v"(a), "v"(b));
    return r;
}

// async global->LDS DMA, 16B per lane; LDS dest = uniform base + lane*16
__device__ __forceinline__ void gl_lds16(const unsigned short* g, unsigned short* l) {
    __builtin_amdgcn_global_load_lds(
        (const __attribute__((address_space(1))) unsigned int*)(const void*)g,
        (__attribute__((address_space(3))) unsigned int*)(void*)l, 16, 0, 0);
}

// ---------------- Router: RMSNorm + logits + top2 + scatter + x->bf16 ----------------
// one wave per token; 4 waves per block
__global__ void router_kernel(const float* __restrict__ x,
                              const float* __restrict__ rscale,
                              const float* __restrict__ rw,
                              const float* __restrict__ pes,
                              int* __restrict__ cursor,
                              int* __restrict__ tok_slot,
                              float* __restrict__ w_slot,
                              unsigned short* __restrict__ xb)
{
    const int wave = threadIdx.x >> 6;
    const int lane = threadIdx.x & 63;
    const int t = blockIdx.x * 4 + wave;
    const float* xt = x + (size_t)t * ND;
    unsigned short* xbt = xb + (size_t)t * ND;

    float part[NE];
#pragma unroll
    for (int e = 0; e < NE; ++e) part[e] = 0.f;
    float ss = 0.f;

#pragma unroll
    for (int i = 0; i < 4; ++i) {
        int d = (lane + 64 * i) * 4;
        float4 xv = *(const float4*)(xt + d);
        float4 sv = *(const float4*)(rscale + d);
        // side-effect: write bf16 copy of x
        s16x4 o;
        o[0] = (short)f2bf(xv.x); o[1] = (short)f2bf(xv.y);
        o[2] = (short)f2bf(xv.z); o[3] = (short)f2bf(xv.w);
        *(s16x4*)(xbt + d) = o;
        float xs[4] = {xv.x, xv.y, xv.z, xv.w};
        float sc[4] = {sv.x, sv.y, sv.z, sv.w};
        const float* rwp = rw + (size_t)d * NE;
#pragma unroll
        for (int c = 0; c < 4; ++c) {
            float v = xs[c];
            ss += v * v;
            float xr = v * sc[c];
            float4 r0 = *(const float4*)(rwp + c * NE);
            float4 r1 = *(const float4*)(rwp + c * NE + 4);
            part[0] += xr * r0.x; part[1] += xr * r0.y;
            part[2] += xr * r0.z; part[3] += xr * r0.w;
            part[4] += xr * r1.x; part[5] += xr * r1.y;
            part[6] += xr * r1.z; part[7] += xr * r1.w;
        }
    }
#pragma unroll
    for (int off = 32; off > 0; off >>= 1) {
        ss += __shfl_xor(ss, off, 64);
#pragma unroll
        for (int e = 0; e < NE; ++e) part[e] += __shfl_xor(part[e], off, 64);
    }
    if (lane == 0) {
        float rinv = rsqrtf(ss * (1.f / ND) + 1e-6f) * rsqrtf((float)ND);
        float lg[NE];
#pragma unroll
        for (int e = 0; e < NE; ++e) lg[e] = part[e] * rinv;
        int i0 = 0; float b0 = lg[0];
#pragma unroll
        for (int e = 1; e < NE; ++e) if (lg[e] > b0) { b0 = lg[e]; i0 = e; }
        int i1 = -1; float b1 = -INFINITY;
#pragma unroll
        for (int e = 0; e < NE; ++e) if (e != i0 && lg[e] > b1) { b1 = lg[e]; i1 = e; }
        float e1 = expf(b1 - b0);
        float denom = 1.f + e1;
        float w0 = pes[i0] / denom;
        float w1 = pes[i1] * e1 / denom;
        int s0 = atomicAdd(&cursor[i0], 1);
        tok_slot[i0 * NTOK + s0] = t; w_slot[i0 * NTOK + s0] = w0;
        int s1 = atomicAdd(&cursor[i1], 1);
        tok_slot[i1 * NTOK + s1] = t; w_slot[i1 * NTOK + s1] = w1;
    }
}

// ---------------- prep_weights: lw [E][H][D] fp32 -> lwT bf16 [E][D][H] only ----------
// (gw fp32->bf16 conversion is fused into gate_gemm's B staging)
#define TL_BLOCKS ((ND/64)*(NH/64)*NE)       // 4096
__global__ __launch_bounds__(256) void prep_weights(const float* __restrict__ lw,
                                                    unsigned short* __restrict__ lwT)
{
    const int b2 = blockIdx.x;
    const int tid = threadIdx.x;
    const int d0 = (b2 & 15) * 64;
    const int h0 = ((b2 >> 4) & 31) * 64;
    const int e  = b2 >> 9;
    __shared__ unsigned short T[64][66];
    {
        const int hr = tid >> 2;
        const int dc = (tid & 3) * 16;
        const float* p = lw + ((size_t)e * NH + h0 + hr) * ND + d0 + dc;
        float t[16];
        *(float4*)&t[0]  = *(const float4*)(p);
        *(float4*)&t[4]  = *(const float4*)(p + 4);
        *(float4*)&t[8]  = *(const float4*)(p + 8);
        *(float4*)&t[12] = *(const float4*)(p + 12);
#pragma unroll
        for (int i = 0; i < 8; ++i) {
            unsigned pk = (unsigned)f2bf(t[2 * i]) | ((unsigned)f2bf(t[2 * i + 1]) << 16);
            *(unsigned*)&T[hr][dc + 2 * i] = pk;
        }
    }
    __syncthreads();
    {
        const int dr = tid >> 2;
        const int hc = (tid & 3) * 16;
        s16x8 o0, o1;
#pragma unroll
        for (int i = 0; i < 8; ++i) o0[i] = (short)T[hc + i][dr];
#pragma unroll
        for (int i = 0; i < 8; ++i) o1[i] = (short)T[hc + 8 + i][dr];
        unsigned short* q = lwT + ((size_t)e * ND + d0 + dr) * NH + h0 + hc;
        *(s16x8*)(q)     = o0;
        *(s16x8*)(q + 8) = o1;
    }
}

// ---------------- gate GEMM (bf16 MFMA; A via global_load_lds, B fp32->bf16 fused) ----
#define BM 128
#define BH 64
#define BK 32
__global__ __launch_bounds__(256, 3) void gate_gemm(
    const unsigned short* __restrict__ xb, const float* __restrict__ gw,
    const int* __restrict__ cursor,
    const int* __restrict__ tok_slot, const float* __restrict__ w_slot,
    unsigned short* __restrict__ act)
{
    const int e = blockIdx.z;
    const int n = cursor[e];
    const int row0 = blockIdx.y * BM;
    if (row0 >= n) return;
    const int b0 = e * NTOK;
    const int h0 = blockIdx.x * BH;

    __shared__ unsigned short As[BM][BK];
    __shared__ unsigned short Bs[BM][BK];   // rows = g*64 + hh
    __shared__ int toks[BM];
    __shared__ float swv[BM];

    const int tid = threadIdx.x;
    if (tid < BM) {
        int r = row0 + tid;
        toks[tid] = (r < n) ? tok_slot[b0 + r] : 0;
        swv[tid]  = (r < n) ? w_slot[b0 + r] : 0.f;
    }
    __syncthreads();

    const int lane = tid & 63;
    const int wid  = tid >> 6;
    const int wm = wid & 1;
    const int wn = wid >> 1;

    const int drow = lane >> 2;
    const int c8  = (((lane & 3) - ((lane >> 3) & 3)) & 3) * 8;
    const int ar0 = wid * 32 + drow;
    const unsigned short* asrc0 = xb + (size_t)toks[ar0] * ND + c8;
    const unsigned short* asrc1 = xb + (size_t)toks[ar0 + 16] * ND + c8;
    const int br0 = wid * 32 + drow;
    const int br1 = br0 + 16;
    // B staged from fp32 gw with on-the-fly bf16 convert; LDS placement matches
    // the global_load_lds convention: LDS[row][(lane&3)*8] <- global[row][c8]
    const float* bsrc0 = gw + (((size_t)e * 2 + (br0 >> 6)) * NH + h0 + (br0 & 63)) * ND + c8;
    const float* bsrc1 = gw + (((size_t)e * 2 + (br1 >> 6)) * NH + h0 + (br1 & 63)) * ND + c8;
    unsigned short* bdst0 = &Bs[br0][(lane & 3) * 8];
    unsigned short* bdst1 = &Bs[br1][(lane & 3) * 8];

    f32x4 acc[2][4][2];
#pragma unroll
    for (int gg = 0; gg < 2; ++gg)
#pragma unroll
        for (int i = 0; i < 4; ++i)
#pragma unroll
            for (int j = 0; j < 2; ++j)
                acc[gg][i][j] = (f32x4){0.f, 0.f, 0.f, 0.f};

    const int fr = lane & 15;
    const int pS = (((lane >> 4) + (fr >> 1)) & 3) * 8;

    for (int k0 = 0; k0 < ND; k0 += BK) {
        // issue fp32 B loads first so they overlap the A DMA
        f32x4 b00 = *(const f32x4*)(bsrc0 + k0);
        f32x4 b01 = *(const f32x4*)(bsrc0 + k0 + 4);
        f32x4 b10 = *(const f32x4*)(bsrc1 + k0);
        f32x4 b11 = *(const f32x4*)(bsrc1 + k0 + 4);
        gl_lds16(asrc0 + k0, &As[wid * 32][0]);
        gl_lds16(asrc1 + k0, &As[wid * 32 + 16][0]);
        u32x4 w0, w1;
        w0[0] = pk2(b00[0], b00[1]); w0[1] = pk2(b00[2], b00[3]);
        w0[2] = pk2(b01[0], b01[1]); w0[3] = pk2(b01[2], b01[3]);
        w1[0] = pk2(b10[0], b10[1]); w1[1] = pk2(b10[2], b10[3]);
        w1[2] = pk2(b11[0], b11[1]); w1[3] = pk2(b11[2], b11[3]);
        *(u32x4*)bdst0 = w0;
        *(u32x4*)bdst1 = w1;
        __syncthreads();

        s16x8 af[4], bfr[2][2];
#pragma unroll
        for (int i = 0; i < 4; ++i)
            af[i] = *(const s16x8*)&As[wm * 64 + i * 16 + fr][pS];
#pragma unroll
        for (int gg = 0; gg < 2; ++gg)
#pragma unroll
            for (int j = 0; j < 2; ++j)
                bfr[gg][j] = *(const s16x8*)&Bs[gg * 64 + wn * 32 + j * 16 + fr][pS];
#pragma unroll
        for (int gg = 0; gg < 2; ++gg)
#pragma unroll
            for (int i = 0; i < 4; ++i)
#pragma unroll
                for (int j = 0; j < 2; ++j)
                    acc[gg][i][j] = __builtin_amdgcn_mfma_f32_16x16x32_bf16(
                        af[i], bfr[gg][j], acc[gg][i][j], 0, 0, 0);
        __syncthreads();
    }

    const int rb = (lane >> 4) * 4;
#pragma unroll
    for (int i = 0; i < 4; ++i)
#pragma unroll
        for (int r = 0; r < 4; ++r) {
            int ml = wm * 64 + i * 16 + rb + r;
            int rr = row0 + ml;
            if (rr < n) {
                float w = swv[ml];
#pragma unroll
                for (int j = 0; j < 2; ++j) {
                    float g0v = acc[0][i][j][r];
                    float g1v = acc[1][i][j][r];
                    float u = 0.7978845608028654f * (g0v + 0.044715f * g0v * g0v * g0v);
                    float ex = __expf(2.f * u);
                    float th = 1.f - 2.f / (ex + 1.f);
                    float a = 0.5f * g0v * (1.f + th) * g1v * w;
                    act[(size_t)(b0 + rr) * NH + (h0 + wn * 32 + j * 16 + fr)] = f2bf(a);
                }
            }
        }
}

// ---------------- down GEMM (bf16 MFMA + global_load_lds, split-K=2) ----------------
#define DBM 128
#define DBN 128
#define DBK 32
#define KSPLIT 2
#define KC (NH / KSPLIT)
__global__ __launch_bounds__(256, 3) void down_gemm(
    const unsigned short* __restrict__ act, const unsigned short* __restrict__ lwT,
    const int* __restrict__ cursor,
    const int* __restrict__ tok_slot, float* __restrict__ out)
{
    const int e  = blockIdx.z >> 1;
    const int kc = blockIdx.z & 1;
    const int n = cursor[e];
    const int row0 = blockIdx.y * DBM;
    if (row0 >= n) return;
    const int b0 = e * NTOK;
    const int d0 = blockIdx.x * DBN;

    __shared__ unsigned short As[DBM][DBK];
    __shared__ unsigned short Bs[DBN][DBK];
    __shared__ int stok[DBM];

    const int tid = threadIdx.x;
    if (tid < DBM) {
        int r = row0 + tid;
        stok[tid] = (r < n) ? tok_slot[b0 + r] : 0;
    }
    __syncthreads();

    const int lane = tid & 63;
    const int wid  = tid >> 6;
    const int wm = wid & 1;
    const int wn = wid >> 1;

    const int drow = lane >> 2;
    const int c8  = (((lane & 3) - ((lane >> 3) & 3)) & 3) * 8;
    const int ar0 = wid * 32 + drow;
    const int rr0 = row0 + ar0, rr1 = rr0 + 16;
    const int sl0 = b0 + (rr0 < n ? rr0 : 0);
    const int sl1 = b0 + (rr1 < n ? rr1 : 0);
    const unsigned short* asrc0 = act + (size_t)sl0 * NH + kc * KC + c8;
    const unsigned short* asrc1 = act + (size_t)sl1 * NH + kc * KC + c8;
    const unsigned short* bsrc0 = lwT + ((size_t)e * ND + d0 + ar0) * NH + kc * KC + c8;
    const unsigned short* bsrc1 = bsrc0 + 16 * NH;

    f32x4 acc[4][4];
#pragma unroll
    for (int i = 0; i < 4; ++i)
#pragma unroll
        for (int j = 0; j < 4; ++j)
            acc[i][j] = (f32x4){0.f, 0.f, 0.f, 0.f};

    const int fr = lane & 15;
    const int pS = (((lane >> 4) + (fr >> 1)) & 3) * 8;

    for (int k0 = 0; k0 < KC; k0 += DBK) {
        gl_lds16(asrc0 + k0, &As[wid * 32][0]);
        gl_lds16(asrc1 + k0, &As[wid * 32 + 16][0]);
        gl_lds16(bsrc0 + k0, &Bs[wid * 32][0]);
        gl_lds16(bsrc1 + k0, &Bs[wid * 32 + 16][0]);
        __syncthreads();

        s16x8 af[4], bfr[4];
#pragma unroll
        for (int i = 0; i < 4; ++i)
            af[i] = *(const s16x8*)&As[wm * 64 + i * 16 + fr][pS];
#pragma unroll
        for (int j = 0; j < 4; ++j)
            bfr[j] = *(const s16x8*)&Bs[wn * 64 + j * 16 + fr][pS];
#pragma unroll
        for (int i = 0; i < 4; ++i)
#pragma unroll
            for (int j = 0; j < 4; ++j)
                acc[i][j] = __builtin_amdgcn_mfma_f32_16x16x32_bf16(af[i], bfr[j], acc[i][j], 0, 0, 0);
        __syncthreads();
    }

    const int rb = (lane >> 4) * 4;
#pragma unroll
    for (int i = 0; i < 4; ++i)
#pragma unroll
        for (int r = 0; r < 4; ++r) {
            int ml = wm * 64 + i * 16 + rb + r;
            int rr = row0 + ml;
            if (rr < n) {
                int tok = stok[ml];
#pragma unroll
                for (int j = 0; j < 4; ++j)
                    atomicAdd(&out[(size_t)tok * ND + d0 + wn * 64 + j * 16 + fr],
                              acc[i][j][r]);
            }
        }
}

extern "C" void kernel_launch(void* const* d_in, const int* in_sizes, int n_in,
                              void* d_out, int out_size, void* d_ws, size_t ws_size,
                              hipStream_t stream)
{
    const float* x      = (const float*)d_in[0];
    const float* rscale = (const float*)d_in[1];
    const float* rw     = (const float*)d_in[2];
    const float* gw     = (const float*)d_in[3];
    const float* lw     = (const float*)d_in[4];
    const float* pes    = (const float*)d_in[5];
    float* out = (float*)d_out;

    // workspace layout (bytes):
    //   0          cursor[8] (zeroed, doubles as counts)
    //   128        tok_slot[8][2048]        65536
    //   65664      w_slot[8][2048]          65536
    //   131200     xb  bf16 [2048][1024]     4194304
    //   4325504    act bf16 [8*2048][2048]  67108864
    //   71434368   lwT bf16 [8][1024][2048] 33554432  -> end ~105 MB
    char* ws = (char*)d_ws;
    int* cursor = (int*)ws;
    int*   tok_slot      = (int*)(ws + 128);
    float* w_slot        = (float*)(ws + 65664);
    unsigned short* xb   = (unsigned short*)(ws + 131200);
    unsigned short* act  = (unsigned short*)(ws + 4325504);
    unsigned short* lwT  = (unsigned short*)(ws + 71434368);

    hipMemsetAsync(d_ws, 0, 128, stream);
    hipMemsetAsync(d_out, 0, (size_t)out_size * sizeof(float), stream);

    router_kernel<<<NTOK / 4, 256, 0, stream>>>(x, rscale, rw, pes, cursor,
                                                tok_slot, w_slot, xb);

    prep_weights<<<TL_BLOCKS, 256, 0, stream>>>(lw, lwT);

    dim3 g2(NH / BH, NTOK / BM, NE);   // 32 x 16 x 8, early-exit
    gate_gemm<<<g2, 256, 0, stream>>>(xb, gw, cursor, tok_slot, w_slot, act);

    dim3 g3(ND / DBN, NTOK / DBM, NE * KSPLIT); // 8 x 16 x 16
    down_gemm<<<g3, 256, 0, stream>>>(act, lwT, cursor, tok_slot, out);
}

// Round 2
// 418.385 us; speedup vs baseline: 1.0373x; 1.0273x over previous
//
#include <hip/hip_runtime.h>
#include <math.h>

#define NB 2
#define NL 1024
#define ND 1024
#define NH 2048
#define NE 8
#define NTOK (NB*NL)      // 2048 tokens; per-expert slot capacity = NTOK
#define NSLOT (NTOK*2)

typedef float f32x4 __attribute__((ext_vector_type(4)));
typedef short s16x8 __attribute__((ext_vector_type(8)));
typedef short s16x4 __attribute__((ext_vector_type(4)));
typedef unsigned u32x4 __attribute__((ext_vector_type(4)));

__device__ __forceinline__ unsigned short f2bf(float f) {
    union { float f; unsigned u; } v; v.f = f;
    unsigned r = v.u + 0x7FFFu + ((v.u >> 16) & 1u);
    return (unsigned short)(r >> 16);
}

// packed fp32->bf16 RNE convert (2 elems / inst); matches f2bf rounding
__device__ __forceinline__ unsigned pk2(float a, float b) {
    unsigned r;
    asm("v_cvt_pk_bf16_f32 %0, %1, %2" : "=v"(r) : "v"(a), "v"(b));
    return r;
}

// async global->LDS DMA, 16B per lane; LDS dest = uniform base + lane*16
__device__ __forceinline__ void gl_lds16(const unsigned short* g, unsigned short* l) {
    __builtin_amdgcn_global_load_lds(
        (const __attribute__((address_space(1))) unsigned int*)(const void*)g,
        (__attribute__((address_space(3))) unsigned int*)(void*)l, 16, 0, 0);
}

// ---------------- Router: RMSNorm + logits + top2 + scatter + x->bf16 ----------------
// one wave per token; 4 waves per block
__global__ void router_kernel(const float* __restrict__ x,
                              const float* __restrict__ rscale,
                              const float* __restrict__ rw,
                              const float* __restrict__ pes,
                              int* __restrict__ cursor,
                              int* __restrict__ tok_slot,
                              float* __restrict__ w_slot,
                              unsigned short* __restrict__ xb)
{
    const int wave = threadIdx.x >> 6;
    const int lane = threadIdx.x & 63;
    const int t = blockIdx.x * 4 + wave;
    const float* xt = x + (size_t)t * ND;
    unsigned short* xbt = xb + (size_t)t * ND;

    float part[NE];
#pragma unroll
    for (int e = 0; e < NE; ++e) part[e] = 0.f;
    float ss = 0.f;

#pragma unroll
    for (int i = 0; i < 4; ++i) {
        int d = (lane + 64 * i) * 4;
        float4 xv = *(const float4*)(xt + d);
        float4 sv = *(const float4*)(rscale + d);
        // side-effect: write bf16 copy of x
        s16x4 o;
        o[0] = (short)f2bf(xv.x); o[1] = (short)f2bf(xv.y);
        o[2] = (short)f2bf(xv.z); o[3] = (short)f2bf(xv.w);
        *(s16x4*)(xbt + d) = o;
        float xs[4] = {xv.x, xv.y, xv.z, xv.w};
        float sc[4] = {sv.x, sv.y, sv.z, sv.w};
        const float* rwp = rw + (size_t)d * NE;
#pragma unroll
        for (int c = 0; c < 4; ++c) {
            float v = xs[c];
            ss += v * v;
            float xr = v * sc[c];
            float4 r0 = *(const float4*)(rwp + c * NE);
            float4 r1 = *(const float4*)(rwp + c * NE + 4);
            part[0] += xr * r0.x; part[1] += xr * r0.y;
            part[2] += xr * r0.z; part[3] += xr * r0.w;
            part[4] += xr * r1.x; part[5] += xr * r1.y;
            part[6] += xr * r1.z; part[7] += xr * r1.w;
        }
    }
#pragma unroll
    for (int off = 32; off > 0; off >>= 1) {
        ss += __shfl_xor(ss, off, 64);
#pragma unroll
        for (int e = 0; e < NE; ++e) part[e] += __shfl_xor(part[e], off, 64);
    }
    if (lane == 0) {
        float rinv = rsqrtf(ss * (1.f / ND) + 1e-6f) * rsqrtf((float)ND);
        float lg[NE];
#pragma unroll
        for (int e = 0; e < NE; ++e) lg[e] = part[e] * rinv;
        int i0 = 0; float b0 = lg[0];
#pragma unroll
        for (int e = 1; e < NE; ++e) if (lg[e] > b0) { b0 = lg[e]; i0 = e; }
        int i1 = -1; float b1 = -INFINITY;
#pragma unroll
        for (int e = 0; e < NE; ++e) if (e != i0 && lg[e] > b1) { b1 = lg[e]; i1 = e; }
        float e1 = expf(b1 - b0);
        float denom = 1.f + e1;
        float w0 = pes[i0] / denom;
        float w1 = pes[i1] * e1 / denom;
        int s0 = atomicAdd(&cursor[i0], 1);
        tok_slot[i0 * NTOK + s0] = t; w_slot[i0 * NTOK + s0] = w0;
        int s1 = atomicAdd(&cursor[i1], 1);
        tok_slot[i1 * NTOK + s1] = t; w_slot[i1 * NTOK + s1] = w1;
    }
}

// ---------------- prep_weights: lw [E][H][D] fp32 -> lwT bf16 [E][D][H] only ----------
// (gw fp32->bf16 conversion is fused into gate_gemm's B staging)
#define TL_BLOCKS ((ND/64)*(NH/64)*NE)       // 4096
__global__ __launch_bounds__(256) void prep_weights(const float* __restrict__ lw,
                                                    unsigned short* __restrict__ lwT)
{
    const int b2 = blockIdx.x;
    const int tid = threadIdx.x;
    const int d0 = (b2 & 15) * 64;
    const int h0 = ((b2 >> 4) & 31) * 64;
    const int e  = b2 >> 9;
    __shared__ unsigned short T[64][66];
    {
        const int hr = tid >> 2;
        const int dc = (tid & 3) * 16;
        const float* p = lw + ((size_t)e * NH + h0 + hr) * ND + d0 + dc;
        float t[16];
        *(float4*)&t[0]  = *(const float4*)(p);
        *(float4*)&t[4]  = *(const float4*)(p + 4);
        *(float4*)&t[8]  = *(const float4*)(p + 8);
        *(float4*)&t[12] = *(const float4*)(p + 12);
#pragma unroll
        for (int i = 0; i < 8; ++i) {
            unsigned pk = (unsigned)f2bf(t[2 * i]) | ((unsigned)f2bf(t[2 * i + 1]) << 16);
            *(unsigned*)&T[hr][dc + 2 * i] = pk;
        }
    }
    __syncthreads();
    {
        const int dr = tid >> 2;
        const int hc = (tid & 3) * 16;
        s16x8 o0, o1;
#pragma unroll
        for (int i = 0; i < 8; ++i) o0[i] = (short)T[hc + i][dr];
#pragma unroll
        for (int i = 0; i < 8; ++i) o1[i] = (short)T[hc + 8 + i][dr];
        unsigned short* q = lwT + ((size_t)e * ND + d0 + dr) * NH + h0 + hc;
        *(s16x8*)(q)     = o0;
        *(s16x8*)(q + 8) = o1;
    }
}

// ---------------- gate GEMM (bf16 MFMA; A via global_load_lds, B fp32->bf16 fused) ----
// double-buffered LDS, B prefetched one tile ahead (T14 issue-early/write-late)
#define BM 128
#define BH 64
#define BK 32
__global__ __launch_bounds__(256, 4) void gate_gemm(
    const unsigned short* __restrict__ xb, const float* __restrict__ gw,
    const int* __restrict__ cursor,
    const int* __restrict__ tok_slot, const float* __restrict__ w_slot,
    unsigned short* __restrict__ act)
{
    const int e = blockIdx.z;
    const int n = cursor[e];
    const int row0 = blockIdx.y * BM;
    if (row0 >= n) return;
    const int b0 = e * NTOK;
    const int h0 = blockIdx.x * BH;

    __shared__ unsigned short As[2][BM][BK];
    __shared__ unsigned short Bs[2][BM][BK];   // rows = g*64 + hh
    __shared__ int toks[BM];
    __shared__ float swv[BM];

    const int tid = threadIdx.x;
    if (tid < BM) {
        int r = row0 + tid;
        toks[tid] = (r < n) ? tok_slot[b0 + r] : 0;
        swv[tid]  = (r < n) ? w_slot[b0 + r] : 0.f;
    }
    __syncthreads();

    const int lane = tid & 63;
    const int wid  = tid >> 6;
    const int wm = wid & 1;
    const int wn = wid >> 1;

    const int drow = lane >> 2;
    const int c8  = (((lane & 3) - ((lane >> 3) & 3)) & 3) * 8;
    const int ar0 = wid * 32 + drow;
    const unsigned short* asrc0 = xb + (size_t)toks[ar0] * ND + c8;
    const unsigned short* asrc1 = xb + (size_t)toks[ar0 + 16] * ND + c8;
    const int br0 = wid * 32 + drow;
    const int br1 = br0 + 16;
    // B staged from fp32 gw with on-the-fly bf16 convert; LDS placement matches
    // the global_load_lds convention: LDS[row][(lane&3)*8] <- global[row][c8]
    const float* bsrc0 = gw + (((size_t)e * 2 + (br0 >> 6)) * NH + h0 + (br0 & 63)) * ND + c8;
    const float* bsrc1 = gw + (((size_t)e * 2 + (br1 >> 6)) * NH + h0 + (br1 & 63)) * ND + c8;
    const int bc = (lane & 3) * 8;

    f32x4 acc[2][4][2];
#pragma unroll
    for (int gg = 0; gg < 2; ++gg)
#pragma unroll
        for (int i = 0; i < 4; ++i)
#pragma unroll
            for (int j = 0; j < 2; ++j)
                acc[gg][i][j] = (f32x4){0.f, 0.f, 0.f, 0.f};

    const int fr = lane & 15;
    const int pS = (((lane >> 4) + (fr >> 1)) & 3) * 8;

    const int NT = ND / BK;   // 32

    // prologue: stage tile 0 into buffer 0
    {
        f32x4 b00 = *(const f32x4*)(bsrc0);
        f32x4 b01 = *(const f32x4*)(bsrc0 + 4);
        f32x4 b10 = *(const f32x4*)(bsrc1);
        f32x4 b11 = *(const f32x4*)(bsrc1 + 4);
        gl_lds16(asrc0, &As[0][wid * 32][0]);
        gl_lds16(asrc1, &As[0][wid * 32 + 16][0]);
        u32x4 w0, w1;
        w0[0] = pk2(b00[0], b00[1]); w0[1] = pk2(b00[2], b00[3]);
        w0[2] = pk2(b01[0], b01[1]); w0[3] = pk2(b01[2], b01[3]);
        w1[0] = pk2(b10[0], b10[1]); w1[1] = pk2(b10[2], b10[3]);
        w1[2] = pk2(b11[0], b11[1]); w1[3] = pk2(b11[2], b11[3]);
        *(u32x4*)&Bs[0][br0][bc] = w0;
        *(u32x4*)&Bs[0][br1][bc] = w1;
    }
    __syncthreads();

    for (int t = 0; t < NT; ++t) {
        const int cur = t & 1;
        const int nxt = cur ^ 1;
        const int k1 = (t + 1) * BK;
        const bool more = (t + 1 < NT);

        // issue-early: next tile's loads overlap this tile's compute
        f32x4 n00, n01, n10, n11;
        if (more) {
            n00 = *(const f32x4*)(bsrc0 + k1);
            n01 = *(const f32x4*)(bsrc0 + k1 + 4);
            n10 = *(const f32x4*)(bsrc1 + k1);
            n11 = *(const f32x4*)(bsrc1 + k1 + 4);
            gl_lds16(asrc0 + k1, &As[nxt][wid * 32][0]);
            gl_lds16(asrc1 + k1, &As[nxt][wid * 32 + 16][0]);
        }

        s16x8 af[4], bfr[2][2];
#pragma unroll
        for (int i = 0; i < 4; ++i)
            af[i] = *(const s16x8*)&As[cur][wm * 64 + i * 16 + fr][pS];
#pragma unroll
        for (int gg = 0; gg < 2; ++gg)
#pragma unroll
            for (int j = 0; j < 2; ++j)
                bfr[gg][j] = *(const s16x8*)&Bs[cur][gg * 64 + wn * 32 + j * 16 + fr][pS];
#pragma unroll
        for (int gg = 0; gg < 2; ++gg)
#pragma unroll
            for (int i = 0; i < 4; ++i)
#pragma unroll
                for (int j = 0; j < 2; ++j)
                    acc[gg][i][j] = __builtin_amdgcn_mfma_f32_16x16x32_bf16(
                        af[i], bfr[gg][j], acc[gg][i][j], 0, 0, 0);

        // write-late: convert + store next B tile after this tile's compute
        if (more) {
            u32x4 w0, w1;
            w0[0] = pk2(n00[0], n00[1]); w0[1] = pk2(n00[2], n00[3]);
            w0[2] = pk2(n01[0], n01[1]); w0[3] = pk2(n01[2], n01[3]);
            w1[0] = pk2(n10[0], n10[1]); w1[1] = pk2(n10[2], n10[3]);
            w1[2] = pk2(n11[0], n11[1]); w1[3] = pk2(n11[2], n11[3]);
            *(u32x4*)&Bs[nxt][br0][bc] = w0;
            *(u32x4*)&Bs[nxt][br1][bc] = w1;
        }
        __syncthreads();
    }

    const int rb = (lane >> 4) * 4;
#pragma unroll
    for (int i = 0; i < 4; ++i)
#pragma unroll
        for (int r = 0; r < 4; ++r) {
            int ml = wm * 64 + i * 16 + rb + r;
            int rr = row0 + ml;
            if (rr < n) {
                float w = swv[ml];
#pragma unroll
                for (int j = 0; j < 2; ++j) {
                    float g0v = acc[0][i][j][r];
                    float g1v = acc[1][i][j][r];
                    float u = 0.7978845608028654f * (g0v + 0.044715f * g0v * g0v * g0v);
                    float ex = __expf(2.f * u);
                    float th = 1.f - 2.f / (ex + 1.f);
                    float a = 0.5f * g0v * (1.f + th) * g1v * w;
                    act[(size_t)(b0 + rr) * NH + (h0 + wn * 32 + j * 16 + fr)] = f2bf(a);
                }
            }
        }
}

// ---------------- down GEMM (bf16 MFMA, double-buffered gl_lds prefetch, split-K=2) --
#define DBM 128
#define DBN 128
#define DBK 32
#define KSPLIT 2
#define KC (NH / KSPLIT)
__global__ __launch_bounds__(256, 4) void down_gemm(
    const unsigned short* __restrict__ act, const unsigned short* __restrict__ lwT,
    const int* __restrict__ cursor,
    const int* __restrict__ tok_slot, float* __restrict__ out)
{
    const int e  = blockIdx.z >> 1;
    const int kc = blockIdx.z & 1;
    const int n = cursor[e];
    const int row0 = blockIdx.y * DBM;
    if (row0 >= n) return;
    const int b0 = e * NTOK;
    const int d0 = blockIdx.x * DBN;

    __shared__ unsigned short As[2][DBM][DBK];
    __shared__ unsigned short Bs[2][DBN][DBK];
    __shared__ int stok[DBM];

    const int tid = threadIdx.x;
    if (tid < DBM) {
        int r = row0 + tid;
        stok[tid] = (r < n) ? tok_slot[b0 + r] : 0;
    }
    __syncthreads();

    const int lane = tid & 63;
    const int wid  = tid >> 6;
    const int wm = wid & 1;
    const int wn = wid >> 1;

    const int drow = lane >> 2;
    const int c8  = (((lane & 3) - ((lane >> 3) & 3)) & 3) * 8;
    const int ar0 = wid * 32 + drow;
    const int rr0 = row0 + ar0, rr1 = rr0 + 16;
    const int sl0 = b0 + (rr0 < n ? rr0 : 0);
    const int sl1 = b0 + (rr1 < n ? rr1 : 0);
    const unsigned short* asrc0 = act + (size_t)sl0 * NH + kc * KC + c8;
    const unsigned short* asrc1 = act + (size_t)sl1 * NH + kc * KC + c8;
    const unsigned short* bsrc0 = lwT + ((size_t)e * ND + d0 + ar0) * NH + kc * KC + c8;
    const unsigned short* bsrc1 = bsrc0 + 16 * NH;

    f32x4 acc[4][4];
#pragma unroll
    for (int i = 0; i < 4; ++i)
#pragma unroll
        for (int j = 0; j < 4; ++j)
            acc[i][j] = (f32x4){0.f, 0.f, 0.f, 0.f};

    const int fr = lane & 15;
    const int pS = (((lane >> 4) + (fr >> 1)) & 3) * 8;

    const int NT = KC / DBK;   // 32

    // prologue: stage tile 0 into buffer 0
    gl_lds16(asrc0, &As[0][wid * 32][0]);
    gl_lds16(asrc1, &As[0][wid * 32 + 16][0]);
    gl_lds16(bsrc0, &Bs[0][wid * 32][0]);
    gl_lds16(bsrc1, &Bs[0][wid * 32 + 16][0]);
    __syncthreads();

    for (int t = 0; t < NT; ++t) {
        const int cur = t & 1;
        const int nxt = cur ^ 1;
        const int k1 = (t + 1) * DBK;
        if (t + 1 < NT) {
            gl_lds16(asrc0 + k1, &As[nxt][wid * 32][0]);
            gl_lds16(asrc1 + k1, &As[nxt][wid * 32 + 16][0]);
            gl_lds16(bsrc0 + k1, &Bs[nxt][wid * 32][0]);
            gl_lds16(bsrc1 + k1, &Bs[nxt][wid * 32 + 16][0]);
        }

        s16x8 af[4], bfr[4];
#pragma unroll
        for (int i = 0; i < 4; ++i)
            af[i] = *(const s16x8*)&As[cur][wm * 64 + i * 16 + fr][pS];
#pragma unroll
        for (int j = 0; j < 4; ++j)
            bfr[j] = *(const s16x8*)&Bs[cur][wn * 64 + j * 16 + fr][pS];
#pragma unroll
        for (int i = 0; i < 4; ++i)
#pragma unroll
            for (int j = 0; j < 4; ++j)
                acc[i][j] = __builtin_amdgcn_mfma_f32_16x16x32_bf16(af[i], bfr[j], acc[i][j], 0, 0, 0);
        __syncthreads();
    }

    const int rb = (lane >> 4) * 4;
#pragma unroll
    for (int i = 0; i < 4; ++i)
#pragma unroll
        for (int r = 0; r < 4; ++r) {
            int ml = wm * 64 + i * 16 + rb + r;
            int rr = row0 + ml;
            if (rr < n) {
                int tok = stok[ml];
#pragma unroll
                for (int j = 0; j < 4; ++j)
                    atomicAdd(&out[(size_t)tok * ND + d0 + wn * 64 + j * 16 + fr],
                              acc[i][j][r]);
            }
        }
}

extern "C" void kernel_launch(void* const* d_in, const int* in_sizes, int n_in,
                              void* d_out, int out_size, void* d_ws, size_t ws_size,
                              hipStream_t stream)
{
    const float* x      = (const float*)d_in[0];
    const float* rscale = (const float*)d_in[1];
    const float* rw     = (const float*)d_in[2];
    const float* gw     = (const float*)d_in[3];
    const float* lw     = (const float*)d_in[4];
    const float* pes    = (const float*)d_in[5];
    float* out = (float*)d_out;

    // workspace layout (bytes):
    //   0          cursor[8] (zeroed, doubles as counts)
    //   128        tok_slot[8][2048]        65536
    //   65664      w_slot[8][2048]          65536
    //   131200     xb  bf16 [2048][1024]     4194304
    //   4325504    act bf16 [8*2048][2048]  67108864
    //   71434368   lwT bf16 [8][1024][2048] 33554432  -> end ~105 MB
    char* ws = (char*)d_ws;
    int* cursor = (int*)ws;
    int*   tok_slot      = (int*)(ws + 128);
    float* w_slot        = (float*)(ws + 65664);
    unsigned short* xb   = (unsigned short*)(ws + 131200);
    unsigned short* act  = (unsigned short*)(ws + 4325504);
    unsigned short* lwT  = (unsigned short*)(ws + 71434368);

    hipMemsetAsync(d_ws, 0, 128, stream);
    hipMemsetAsync(d_out, 0, (size_t)out_size * sizeof(float), stream);

    router_kernel<<<NTOK / 4, 256, 0, stream>>>(x, rscale, rw, pes, cursor,
                                                tok_slot, w_slot, xb);

    prep_weights<<<TL_BLOCKS, 256, 0, stream>>>(lw, lwT);

    dim3 g2(NH / BH, NTOK / BM, NE);   // 32 x 16 x 8, early-exit
    gate_gemm<<<g2, 256, 0, stream>>>(xb, gw, cursor, tok_slot, w_slot, act);

    dim3 g3(ND / DBN, NTOK / DBM, NE * KSPLIT); // 8 x 16 x 16
    down_gemm<<<g3, 256, 0, stream>>>(act, lwT, cursor, tok_slot, out);
}

// Round 3
// 406.171 us; speedup vs baseline: 1.0685x; 1.0301x over previous
//
#include <hip/hip_runtime.h>
#include <math.h>

#define NB 2
#define NL 1024
#define ND 1024
#define NH 2048
#define NE 8
#define NTOK (NB*NL)      // 2048 tokens; per-expert slot capacity = NTOK
#define NSLOT (NTOK*2)

typedef float f32x4 __attribute__((ext_vector_type(4)));
typedef short s16x8 __attribute__((ext_vector_type(8)));
typedef short s16x4 __attribute__((ext_vector_type(4)));
typedef unsigned u32x4 __attribute__((ext_vector_type(4)));

__device__ __forceinline__ unsigned short f2bf(float f) {
    union { float f; unsigned u; } v; v.f = f;
    unsigned r = v.u + 0x7FFFu + ((v.u >> 16) & 1u);
    return (unsigned short)(r >> 16);
}

// packed fp32->bf16 RNE convert (2 elems / inst); matches f2bf rounding
__device__ __forceinline__ unsigned pk2(float a, float b) {
    unsigned r;
    asm("v_cvt_pk_bf16_f32 %0, %1, %2" : "=v"(r) : "v"(a), "v"(b));
    return r;
}

// ---------------- Router: RMSNorm + logits + top2 + scatter + x->bf16 ----------------
// one wave per token; 4 waves per block
__global__ void router_kernel(const float* __restrict__ x,
                              const float* __restrict__ rscale,
                              const float* __restrict__ rw,
                              const float* __restrict__ pes,
                              int* __restrict__ cursor,
                              int* __restrict__ tok_slot,
                              float* __restrict__ w_slot,
                              int2* __restrict__ t2s,
                              unsigned short* __restrict__ xb)
{
    const int wave = threadIdx.x >> 6;
    const int lane = threadIdx.x & 63;
    const int t = blockIdx.x * 4 + wave;
    const float* xt = x + (size_t)t * ND;
    unsigned short* xbt = xb + (size_t)t * ND;

    float part[NE];
#pragma unroll
    for (int e = 0; e < NE; ++e) part[e] = 0.f;
    float ss = 0.f;

#pragma unroll
    for (int i = 0; i < 4; ++i) {
        int d = (lane + 64 * i) * 4;
        float4 xv = *(const float4*)(xt + d);
        float4 sv = *(const float4*)(rscale + d);
        // side-effect: write bf16 copy of x
        s16x4 o;
        o[0] = (short)f2bf(xv.x); o[1] = (short)f2bf(xv.y);
        o[2] = (short)f2bf(xv.z); o[3] = (short)f2bf(xv.w);
        *(s16x4*)(xbt + d) = o;
        float xs[4] = {xv.x, xv.y, xv.z, xv.w};
        float sc[4] = {sv.x, sv.y, sv.z, sv.w};
        const float* rwp = rw + (size_t)d * NE;
#pragma unroll
        for (int c = 0; c < 4; ++c) {
            float v = xs[c];
            ss += v * v;
            float xr = v * sc[c];
            float4 r0 = *(const float4*)(rwp + c * NE);
            float4 r1 = *(const float4*)(rwp + c * NE + 4);
            part[0] += xr * r0.x; part[1] += xr * r0.y;
            part[2] += xr * r0.z; part[3] += xr * r0.w;
            part[4] += xr * r1.x; part[5] += xr * r1.y;
            part[6] += xr * r1.z; part[7] += xr * r1.w;
        }
    }
#pragma unroll
    for (int off = 32; off > 0; off >>= 1) {
        ss += __shfl_xor(ss, off, 64);
#pragma unroll
        for (int e = 0; e < NE; ++e) part[e] += __shfl_xor(part[e], off, 64);
    }
    if (lane == 0) {
        float rinv = rsqrtf(ss * (1.f / ND) + 1e-6f) * rsqrtf((float)ND);
        float lg[NE];
#pragma unroll
        for (int e = 0; e < NE; ++e) lg[e] = part[e] * rinv;
        int i0 = 0; float b0 = lg[0];
#pragma unroll
        for (int e = 1; e < NE; ++e) if (lg[e] > b0) { b0 = lg[e]; i0 = e; }
        int i1 = -1; float b1 = -INFINITY;
#pragma unroll
        for (int e = 0; e < NE; ++e) if (e != i0 && lg[e] > b1) { b1 = lg[e]; i1 = e; }
        float e1 = expf(b1 - b0);
        float denom = 1.f + e1;
        float w0 = pes[i0] / denom;
        float w1 = pes[i1] * e1 / denom;
        int s0 = atomicAdd(&cursor[i0], 1);
        tok_slot[i0 * NTOK + s0] = t; w_slot[i0 * NTOK + s0] = w0;
        int s1 = atomicAdd(&cursor[i1], 1);
        tok_slot[i1 * NTOK + s1] = t; w_slot[i1 * NTOK + s1] = w1;
        t2s[t] = make_int2(i0 * NTOK + s0, i1 * NTOK + s1);
    }
}

// ---------------- prep_weights: lw [E][H][D] fp32 -> lwT bf16 [E][D][H] only ----------
#define TL_BLOCKS ((ND/64)*(NH/64)*NE)       // 4096
__global__ __launch_bounds__(256) void prep_weights(const float* __restrict__ lw,
                                                    unsigned short* __restrict__ lwT)
{
    const int b2 = blockIdx.x;
    const int tid = threadIdx.x;
    const int d0 = (b2 & 15) * 64;
    const int h0 = ((b2 >> 4) & 31) * 64;
    const int e  = b2 >> 9;
    __shared__ unsigned short T[64][66];
    {
        const int hr = tid >> 2;
        const int dc = (tid & 3) * 16;
        const float* p = lw + ((size_t)e * NH + h0 + hr) * ND + d0 + dc;
        float t[16];
        *(float4*)&t[0]  = *(const float4*)(p);
        *(float4*)&t[4]  = *(const float4*)(p + 4);
        *(float4*)&t[8]  = *(const float4*)(p + 8);
        *(float4*)&t[12] = *(const float4*)(p + 12);
#pragma unroll
        for (int i = 0; i < 8; ++i) {
            unsigned pk = (unsigned)f2bf(t[2 * i]) | ((unsigned)f2bf(t[2 * i + 1]) << 16);
            *(unsigned*)&T[hr][dc + 2 * i] = pk;
        }
    }
    __syncthreads();
    {
        const int dr = tid >> 2;
        const int hc = (tid & 3) * 16;
        s16x8 o0, o1;
#pragma unroll
        for (int i = 0; i < 8; ++i) o0[i] = (short)T[hc + i][dr];
#pragma unroll
        for (int i = 0; i < 8; ++i) o1[i] = (short)T[hc + 8 + i][dr];
        unsigned short* q = lwT + ((size_t)e * ND + d0 + dr) * NH + h0 + hc;
        *(s16x8*)(q)     = o0;
        *(s16x8*)(q + 8) = o1;
    }
}

// ---------------- gate GEMM: reg-staged 2-deep pipeline, no global_load_lds ----------
// A (bf16) and B (fp32 -> bf16 on write) both staged global->reg->LDS so that
// __syncthreads never forces a vmcnt(0) drain of in-flight prefetches (T14).
#define BM 128
#define BH 64
#define BK 32

#define G_ISSUE(Sa0,Sa1,Sb0,Sb1,Sb2,Sb3,k) do { \
    Sa0 = *(const s16x8*)(asrc0 + (k)); \
    Sa1 = *(const s16x8*)(asrc1 + (k)); \
    Sb0 = *(const f32x4*)(bsrc0 + (k)); \
    Sb1 = *(const f32x4*)(bsrc0 + (k) + 4); \
    Sb2 = *(const f32x4*)(bsrc1 + (k)); \
    Sb3 = *(const f32x4*)(bsrc1 + (k) + 4); \
} while(0)

#define G_WRITE(P,Sa0,Sa1,Sb0,Sb1,Sb2,Sb3) do { \
    *(s16x8*)&As[P][arow][acol]      = Sa0; \
    *(s16x8*)&As[P][arow + 16][acol] = Sa1; \
    u32x4 w0_, w1_; \
    w0_[0] = pk2(Sb0[0],Sb0[1]); w0_[1] = pk2(Sb0[2],Sb0[3]); \
    w0_[2] = pk2(Sb1[0],Sb1[1]); w0_[3] = pk2(Sb1[2],Sb1[3]); \
    w1_[0] = pk2(Sb2[0],Sb2[1]); w1_[1] = pk2(Sb2[2],Sb2[3]); \
    w1_[2] = pk2(Sb3[0],Sb3[1]); w1_[3] = pk2(Sb3[2],Sb3[3]); \
    *(u32x4*)&Bs[P][arow][acol]      = w0_; \
    *(u32x4*)&Bs[P][arow + 16][acol] = w1_; \
} while(0)

#define G_COMPUTE(P) do { \
    s16x8 af[4], bfr[2][2]; \
    _Pragma("unroll") \
    for (int i_ = 0; i_ < 4; ++i_) \
        af[i_] = *(const s16x8*)&As[P][wm * 64 + i_ * 16 + fr][pS]; \
    _Pragma("unroll") \
    for (int g_ = 0; g_ < 2; ++g_) \
        _Pragma("unroll") \
        for (int j_ = 0; j_ < 2; ++j_) \
            bfr[g_][j_] = *(const s16x8*)&Bs[P][g_ * 64 + wn * 32 + j_ * 16 + fr][pS]; \
    _Pragma("unroll") \
    for (int g_ = 0; g_ < 2; ++g_) \
        _Pragma("unroll") \
        for (int i_ = 0; i_ < 4; ++i_) \
            _Pragma("unroll") \
            for (int j_ = 0; j_ < 2; ++j_) \
                acc[g_][i_][j_] = __builtin_amdgcn_mfma_f32_16x16x32_bf16( \
                    af[i_], bfr[g_][j_], acc[g_][i_][j_], 0, 0, 0); \
} while(0)

__global__ __launch_bounds__(256, 3) void gate_gemm(
    const unsigned short* __restrict__ xb, const float* __restrict__ gw,
    const int* __restrict__ cursor,
    const int* __restrict__ tok_slot, const float* __restrict__ w_slot,
    unsigned short* __restrict__ act)
{
    const int e = blockIdx.z;
    const int n = cursor[e];
    const int row0 = blockIdx.y * BM;
    if (row0 >= n) return;
    const int b0 = e * NTOK;
    const int h0 = blockIdx.x * BH;

    __shared__ unsigned short As[2][BM][BK];
    __shared__ unsigned short Bs[2][BM][BK];   // rows = g*64 + hh
    __shared__ int toks[BM];
    __shared__ float swv[BM];

    const int tid = threadIdx.x;
    if (tid < BM) {
        int r = row0 + tid;
        toks[tid] = (r < n) ? tok_slot[b0 + r] : 0;
        swv[tid]  = (r < n) ? w_slot[b0 + r] : 0.f;
    }
    __syncthreads();

    const int lane = tid & 63;
    const int wid  = tid >> 6;
    const int wm = wid & 1;
    const int wn = wid >> 1;

    const int drow = lane >> 2;
    const int c8  = (((lane & 3) - ((lane >> 3) & 3)) & 3) * 8;   // swizzled src col
    const int arow = wid * 32 + drow;                              // LDS dest row
    const int acol = (lane & 3) * 8;                               // LDS dest col
    const unsigned short* asrc0 = xb + (size_t)toks[arow] * ND + c8;
    const unsigned short* asrc1 = xb + (size_t)toks[arow + 16] * ND + c8;
    const int br1 = arow + 16;
    const float* bsrc0 = gw + (((size_t)e * 2 + (arow >> 6)) * NH + h0 + (arow & 63)) * ND + c8;
    const float* bsrc1 = gw + (((size_t)e * 2 + (br1 >> 6)) * NH + h0 + (br1 & 63)) * ND + c8;

    f32x4 acc[2][4][2];
#pragma unroll
    for (int gg = 0; gg < 2; ++gg)
#pragma unroll
        for (int i = 0; i < 4; ++i)
#pragma unroll
            for (int j = 0; j < 2; ++j)
                acc[gg][i][j] = (f32x4){0.f, 0.f, 0.f, 0.f};

    const int fr = lane & 15;
    const int pS = (((lane >> 4) + (fr >> 1)) & 3) * 8;

    const int NT = ND / BK;   // 32 (even)

    // two named stage sets: X = even tiles, Y = odd tiles (static reg indexing)
    s16x8 xa0, xa1, ya0, ya1;
    f32x4 xb0, xb1, xb2, xb3, yb0, yb1, yb2, yb3;

    // prologue: issue tiles 0,1; write tile 0 into buf0
    G_ISSUE(xa0, xa1, xb0, xb1, xb2, xb3, 0);
    G_ISSUE(ya0, ya1, yb0, yb1, yb2, yb3, BK);
    G_WRITE(0, xa0, xa1, xb0, xb1, xb2, xb3);
    __syncthreads();

    for (int t = 0; t < NT; t += 2) {
        // even iter: compute tile t from buf0; tile t+1 is in Y regs; prefetch t+2 into X
        if (t + 2 < NT) G_ISSUE(xa0, xa1, xb0, xb1, xb2, xb3, (t + 2) * BK);
        G_COMPUTE(0);
        G_WRITE(1, ya0, ya1, yb0, yb1, yb2, yb3);   // tile t+1 -> buf1
        __syncthreads();
        // odd iter: compute tile t+1 from buf1; prefetch t+3 into Y; write t+2 -> buf0
        if (t + 3 < NT) G_ISSUE(ya0, ya1, yb0, yb1, yb2, yb3, (t + 3) * BK);
        G_COMPUTE(1);
        if (t + 2 < NT) G_WRITE(0, xa0, xa1, xb0, xb1, xb2, xb3);
        __syncthreads();
    }

    const int rb = (lane >> 4) * 4;
#pragma unroll
    for (int i = 0; i < 4; ++i)
#pragma unroll
        for (int r = 0; r < 4; ++r) {
            int ml = wm * 64 + i * 16 + rb + r;
            int rr = row0 + ml;
            if (rr < n) {
                float w = swv[ml];
#pragma unroll
                for (int j = 0; j < 2; ++j) {
                    float g0v = acc[0][i][j][r];
                    float g1v = acc[1][i][j][r];
                    float u = 0.7978845608028654f * (g0v + 0.044715f * g0v * g0v * g0v);
                    float ex = __expf(2.f * u);
                    float th = 1.f - 2.f / (ex + 1.f);
                    float a = 0.5f * g0v * (1.f + th) * g1v * w;
                    act[(size_t)(b0 + rr) * NH + (h0 + wn * 32 + j * 16 + fr)] = f2bf(a);
                }
            }
        }
}

// ---------------- down GEMM: reg-staged 2-deep pipeline, non-atomic partial output ---
#define DBM 128
#define DBN 128
#define DBK 32
#define KSPLIT 2
#define KC (NH / KSPLIT)

#define D_ISSUE(Sa0,Sa1,Sb0,Sb1,k) do { \
    Sa0 = *(const s16x8*)(asrc0 + (k)); \
    Sa1 = *(const s16x8*)(asrc1 + (k)); \
    Sb0 = *(const s16x8*)(bsrc0 + (k)); \
    Sb1 = *(const s16x8*)(bsrc1 + (k)); \
} while(0)

#define D_WRITE(P,Sa0,Sa1,Sb0,Sb1) do { \
    *(s16x8*)&As[P][arow][acol]      = Sa0; \
    *(s16x8*)&As[P][arow + 16][acol] = Sa1; \
    *(s16x8*)&Bs[P][arow][acol]      = Sb0; \
    *(s16x8*)&Bs[P][arow + 16][acol] = Sb1; \
} while(0)

#define D_COMPUTE(P) do { \
    s16x8 af[4], bfr[4]; \
    _Pragma("unroll") \
    for (int i_ = 0; i_ < 4; ++i_) \
        af[i_] = *(const s16x8*)&As[P][wm * 64 + i_ * 16 + fr][pS]; \
    _Pragma("unroll") \
    for (int j_ = 0; j_ < 4; ++j_) \
        bfr[j_] = *(const s16x8*)&Bs[P][wn * 64 + j_ * 16 + fr][pS]; \
    _Pragma("unroll") \
    for (int i_ = 0; i_ < 4; ++i_) \
        _Pragma("unroll") \
        for (int j_ = 0; j_ < 4; ++j_) \
            acc[i_][j_] = __builtin_amdgcn_mfma_f32_16x16x32_bf16( \
                af[i_], bfr[j_], acc[i_][j_], 0, 0, 0); \
} while(0)

__global__ __launch_bounds__(256, 3) void down_gemm(
    const unsigned short* __restrict__ act, const unsigned short* __restrict__ lwT,
    const int* __restrict__ cursor,
    const int* __restrict__ tok_slot, float* __restrict__ partial)
{
    const int e  = blockIdx.z >> 1;
    const int kc = blockIdx.z & 1;
    const int n = cursor[e];
    const int row0 = blockIdx.y * DBM;
    if (row0 >= n) return;
    const int b0 = e * NTOK;
    const int d0 = blockIdx.x * DBN;

    __shared__ unsigned short As[2][DBM][DBK];
    __shared__ unsigned short Bs[2][DBN][DBK];

    const int tid = threadIdx.x;
    const int lane = tid & 63;
    const int wid  = tid >> 6;
    const int wm = wid & 1;
    const int wn = wid >> 1;

    const int drow = lane >> 2;
    const int c8  = (((lane & 3) - ((lane >> 3) & 3)) & 3) * 8;
    const int arow = wid * 32 + drow;
    const int acol = (lane & 3) * 8;
    const int rr0 = row0 + arow, rr1 = rr0 + 16;
    const int sl0 = b0 + (rr0 < n ? rr0 : 0);
    const int sl1 = b0 + (rr1 < n ? rr1 : 0);
    const unsigned short* asrc0 = act + (size_t)sl0 * NH + kc * KC + c8;
    const unsigned short* asrc1 = act + (size_t)sl1 * NH + kc * KC + c8;
    const unsigned short* bsrc0 = lwT + ((size_t)e * ND + d0 + arow) * NH + kc * KC + c8;
    const unsigned short* bsrc1 = bsrc0 + 16 * NH;

    f32x4 acc[4][4];
#pragma unroll
    for (int i = 0; i < 4; ++i)
#pragma unroll
        for (int j = 0; j < 4; ++j)
            acc[i][j] = (f32x4){0.f, 0.f, 0.f, 0.f};

    const int fr = lane & 15;
    const int pS = (((lane >> 4) + (fr >> 1)) & 3) * 8;

    const int NT = KC / DBK;   // 32 (even)

    s16x8 xa0, xa1, xb0, xb1;   // even tiles
    s16x8 ya0, ya1, yb0, yb1;   // odd tiles

    G_UNUSED_SEMI:;
    D_ISSUE(xa0, xa1, xb0, xb1, 0);
    D_ISSUE(ya0, ya1, yb0, yb1, DBK);
    D_WRITE(0, xa0, xa1, xb0, xb1);
    __syncthreads();

    for (int t = 0; t < NT; t += 2) {
        if (t + 2 < NT) D_ISSUE(xa0, xa1, xb0, xb1, (t + 2) * DBK);
        D_COMPUTE(0);
        D_WRITE(1, ya0, ya1, yb0, yb1);
        __syncthreads();
        if (t + 3 < NT) D_ISSUE(ya0, ya1, yb0, yb1, (t + 3) * DBK);
        D_COMPUTE(1);
        if (t + 2 < NT) D_WRITE(0, xa0, xa1, xb0, xb1);
        __syncthreads();
    }

    // non-atomic: write per-slot partial plane [kc][slot][d]
    float* prt = partial + ((size_t)kc * (NE * NTOK)) * ND;
    const int rb = (lane >> 4) * 4;
#pragma unroll
    for (int i = 0; i < 4; ++i)
#pragma unroll
        for (int r = 0; r < 4; ++r) {
            int ml = wm * 64 + i * 16 + rb + r;
            int rr = row0 + ml;
            if (rr < n) {
#pragma unroll
                for (int j = 0; j < 4; ++j)
                    prt[(size_t)(b0 + rr) * ND + d0 + wn * 64 + j * 16 + fr] = acc[i][j][r];
            }
        }
}

// ---------------- gather: out[t] = sum of 4 partial rows (2 slots x 2 kc) ------------
__global__ __launch_bounds__(256) void gather_out(const float* __restrict__ partial,
                                                  const int2* __restrict__ t2s,
                                                  float* __restrict__ out)
{
    const int t = blockIdx.x;
    const int2 ss = t2s[t];
    const size_t plane = (size_t)(NE * NTOK) * ND;
    const float* p00 = partial + (size_t)ss.x * ND;
    const float* p01 = p00 + plane;
    const float* p10 = partial + (size_t)ss.y * ND;
    const float* p11 = p10 + plane;
    const int d = threadIdx.x * 4;
    f32x4 a = *(const f32x4*)(p00 + d);
    f32x4 b = *(const f32x4*)(p01 + d);
    f32x4 c = *(const f32x4*)(p10 + d);
    f32x4 e = *(const f32x4*)(p11 + d);
    f32x4 v = a + b + c + e;
    *(f32x4*)(out + (size_t)t * ND + d) = v;
}

extern "C" void kernel_launch(void* const* d_in, const int* in_sizes, int n_in,
                              void* d_out, int out_size, void* d_ws, size_t ws_size,
                              hipStream_t stream)
{
    const float* x      = (const float*)d_in[0];
    const float* rscale = (const float*)d_in[1];
    const float* rw     = (const float*)d_in[2];
    const float* gw     = (const float*)d_in[3];
    const float* lw     = (const float*)d_in[4];
    const float* pes    = (const float*)d_in[5];
    float* out = (float*)d_out;

    // workspace layout (bytes):
    //   0          cursor[8] (zeroed, doubles as counts)
    //   128        tok_slot[8][2048] int        65536
    //   65664      w_slot[8][2048] f32          65536
    //   131200     t2s[2048] int2               16384
    //   147584     xb  bf16 [2048][1024]        4194304   -> 4341888
    //   4341888    act bf16 [8*2048][2048]      67108864  -> 71450752
    //   71450752   lwT bf16 [8][1024][2048]     33554432  -> 105005184
    //   105005184  partial f32 [2][8*2048][1024] 134217728 -> ~229 MB
    char* ws = (char*)d_ws;
    int* cursor = (int*)ws;
    int*   tok_slot      = (int*)(ws + 128);
    float* w_slot        = (float*)(ws + 65664);
    int2*  t2s           = (int2*)(ws + 131200);
    unsigned short* xb   = (unsigned short*)(ws + 147584);
    unsigned short* act  = (unsigned short*)(ws + 4341888);
    unsigned short* lwT  = (unsigned short*)(ws + 71450752);
    float* partial       = (float*)(ws + 105005184);

    hipMemsetAsync(d_ws, 0, 128, stream);

    router_kernel<<<NTOK / 4, 256, 0, stream>>>(x, rscale, rw, pes, cursor,
                                                tok_slot, w_slot, t2s, xb);

    prep_weights<<<TL_BLOCKS, 256, 0, stream>>>(lw, lwT);

    dim3 g2(NH / BH, NTOK / BM, NE);   // 32 x 16 x 8, early-exit
    gate_gemm<<<g2, 256, 0, stream>>>(xb, gw, cursor, tok_slot, w_slot, act);

    dim3 g3(ND / DBN, NTOK / DBM, NE * KSPLIT); // 8 x 16 x 16
    down_gemm<<<g3, 256, 0, stream>>>(act, lwT, cursor, tok_slot, partial);

    gather_out<<<NTOK, 256, 0, stream>>>(partial, t2s, out);
}

// Round 4
// 403.564 us; speedup vs baseline: 1.0754x; 1.0065x over previous
//
#include <hip/hip_runtime.h>
#include <math.h>

#define NB 2
#define NL 1024
#define ND 1024
#define NH 2048
#define NE 8
#define NTOK (NB*NL)      // 2048 tokens; per-expert slot capacity = NTOK
#define NSLOT (NTOK*2)

typedef float f32x4 __attribute__((ext_vector_type(4)));
typedef short s16x8 __attribute__((ext_vector_type(8)));
typedef short s16x4 __attribute__((ext_vector_type(4)));
typedef unsigned u32x4 __attribute__((ext_vector_type(4)));

__device__ __forceinline__ unsigned short f2bf(float f) {
    union { float f; unsigned u; } v; v.f = f;
    unsigned r = v.u + 0x7FFFu + ((v.u >> 16) & 1u);
    return (unsigned short)(r >> 16);
}

// packed fp32->bf16 RNE convert (2 elems / inst); matches f2bf rounding
__device__ __forceinline__ unsigned pk2(float a, float b) {
    unsigned r;
    asm("v_cvt_pk_bf16_f32 %0, %1, %2" : "=v"(r) : "v"(a), "v"(b));
    return r;
}

#define SBAR() __builtin_amdgcn_sched_barrier(0)

// ---------------- Router: RMSNorm + logits + top2 + scatter + x->bf16 ----------------
// one wave per token; 4 waves per block
__global__ void router_kernel(const float* __restrict__ x,
                              const float* __restrict__ rscale,
                              const float* __restrict__ rw,
                              const float* __restrict__ pes,
                              int* __restrict__ cursor,
                              int* __restrict__ tok_slot,
                              float* __restrict__ w_slot,
                              int2* __restrict__ t2s,
                              unsigned short* __restrict__ xb)
{
    const int wave = threadIdx.x >> 6;
    const int lane = threadIdx.x & 63;
    const int t = blockIdx.x * 4 + wave;
    const float* xt = x + (size_t)t * ND;
    unsigned short* xbt = xb + (size_t)t * ND;

    float part[NE];
#pragma unroll
    for (int e = 0; e < NE; ++e) part[e] = 0.f;
    float ss = 0.f;

#pragma unroll
    for (int i = 0; i < 4; ++i) {
        int d = (lane + 64 * i) * 4;
        float4 xv = *(const float4*)(xt + d);
        float4 sv = *(const float4*)(rscale + d);
        // side-effect: write bf16 copy of x
        s16x4 o;
        o[0] = (short)f2bf(xv.x); o[1] = (short)f2bf(xv.y);
        o[2] = (short)f2bf(xv.z); o[3] = (short)f2bf(xv.w);
        *(s16x4*)(xbt + d) = o;
        float xs[4] = {xv.x, xv.y, xv.z, xv.w};
        float sc[4] = {sv.x, sv.y, sv.z, sv.w};
        const float* rwp = rw + (size_t)d * NE;
#pragma unroll
        for (int c = 0; c < 4; ++c) {
            float v = xs[c];
            ss += v * v;
            float xr = v * sc[c];
            float4 r0 = *(const float4*)(rwp + c * NE);
            float4 r1 = *(const float4*)(rwp + c * NE + 4);
            part[0] += xr * r0.x; part[1] += xr * r0.y;
            part[2] += xr * r0.z; part[3] += xr * r0.w;
            part[4] += xr * r1.x; part[5] += xr * r1.y;
            part[6] += xr * r1.z; part[7] += xr * r1.w;
        }
    }
#pragma unroll
    for (int off = 32; off > 0; off >>= 1) {
        ss += __shfl_xor(ss, off, 64);
#pragma unroll
        for (int e = 0; e < NE; ++e) part[e] += __shfl_xor(part[e], off, 64);
    }
    if (lane == 0) {
        float rinv = rsqrtf(ss * (1.f / ND) + 1e-6f) * rsqrtf((float)ND);
        float lg[NE];
#pragma unroll
        for (int e = 0; e < NE; ++e) lg[e] = part[e] * rinv;
        int i0 = 0; float b0 = lg[0];
#pragma unroll
        for (int e = 1; e < NE; ++e) if (lg[e] > b0) { b0 = lg[e]; i0 = e; }
        int i1 = -1; float b1 = -INFINITY;
#pragma unroll
        for (int e = 0; e < NE; ++e) if (e != i0 && lg[e] > b1) { b1 = lg[e]; i1 = e; }
        float e1 = expf(b1 - b0);
        float denom = 1.f + e1;
        float w0 = pes[i0] / denom;
        float w1 = pes[i1] * e1 / denom;
        int s0 = atomicAdd(&cursor[i0], 1);
        tok_slot[i0 * NTOK + s0] = t; w_slot[i0 * NTOK + s0] = w0;
        int s1 = atomicAdd(&cursor[i1], 1);
        tok_slot[i1 * NTOK + s1] = t; w_slot[i1 * NTOK + s1] = w1;
        t2s[t] = make_int2(i0 * NTOK + s0, i1 * NTOK + s1);
    }
}

// ---------------- prep_weights: lw [E][H][D] fp32 -> lwT bf16 [E][D][H] only ----------
#define TL_BLOCKS ((ND/64)*(NH/64)*NE)       // 4096
__global__ __launch_bounds__(256) void prep_weights(const float* __restrict__ lw,
                                                    unsigned short* __restrict__ lwT)
{
    const int b2 = blockIdx.x;
    const int tid = threadIdx.x;
    const int d0 = (b2 & 15) * 64;
    const int h0 = ((b2 >> 4) & 31) * 64;
    const int e  = b2 >> 9;
    __shared__ unsigned short T[64][66];
    {
        const int hr = tid >> 2;
        const int dc = (tid & 3) * 16;
        const float* p = lw + ((size_t)e * NH + h0 + hr) * ND + d0 + dc;
        float t[16];
        *(float4*)&t[0]  = *(const float4*)(p);
        *(float4*)&t[4]  = *(const float4*)(p + 4);
        *(float4*)&t[8]  = *(const float4*)(p + 8);
        *(float4*)&t[12] = *(const float4*)(p + 12);
#pragma unroll
        for (int i = 0; i < 8; ++i) {
            unsigned pk = (unsigned)f2bf(t[2 * i]) | ((unsigned)f2bf(t[2 * i + 1]) << 16);
            *(unsigned*)&T[hr][dc + 2 * i] = pk;
        }
    }
    __syncthreads();
    {
        const int dr = tid >> 2;
        const int hc = (tid & 3) * 16;
        s16x8 o0, o1;
#pragma unroll
        for (int i = 0; i < 8; ++i) o0[i] = (short)T[hc + i][dr];
#pragma unroll
        for (int i = 0; i < 8; ++i) o1[i] = (short)T[hc + 8 + i][dr];
        unsigned short* q = lwT + ((size_t)e * ND + d0 + dr) * NH + h0 + hc;
        *(s16x8*)(q)     = o0;
        *(s16x8*)(q + 8) = o1;
    }
}

// ---------------- gate GEMM: reg-staged 2-deep pipeline, sched_barrier-pinned --------
// A (bf16) and B (fp32 -> bf16 on write) both staged global->reg->LDS so that
// __syncthreads never forces a vmcnt(0) drain of in-flight prefetches (T14).
// sched_barrier(0) fences pin ISSUE | COMPUTE | WRITE so the register allocator
// cannot sink the loads to their uses (round-3 failure: VGPR=84 proved collapse).
#define BM 128
#define BH 64
#define BK 32

#define G_ISSUE(Sa0,Sa1,Sb0,Sb1,Sb2,Sb3,k) do { \
    Sa0 = *(const s16x8*)(asrc0 + (k)); \
    Sa1 = *(const s16x8*)(asrc1 + (k)); \
    Sb0 = *(const f32x4*)(bsrc0 + (k)); \
    Sb1 = *(const f32x4*)(bsrc0 + (k) + 4); \
    Sb2 = *(const f32x4*)(bsrc1 + (k)); \
    Sb3 = *(const f32x4*)(bsrc1 + (k) + 4); \
} while(0)

#define G_WRITE(P,Sa0,Sa1,Sb0,Sb1,Sb2,Sb3) do { \
    *(s16x8*)&As[P][arow][acol]      = Sa0; \
    *(s16x8*)&As[P][arow + 16][acol] = Sa1; \
    u32x4 w0_, w1_; \
    w0_[0] = pk2(Sb0[0],Sb0[1]); w0_[1] = pk2(Sb0[2],Sb0[3]); \
    w0_[2] = pk2(Sb1[0],Sb1[1]); w0_[3] = pk2(Sb1[2],Sb1[3]); \
    w1_[0] = pk2(Sb2[0],Sb2[1]); w1_[1] = pk2(Sb2[2],Sb2[3]); \
    w1_[2] = pk2(Sb3[0],Sb3[1]); w1_[3] = pk2(Sb3[2],Sb3[3]); \
    *(u32x4*)&Bs[P][arow][acol]      = w0_; \
    *(u32x4*)&Bs[P][arow + 16][acol] = w1_; \
} while(0)

#define G_COMPUTE(P) do { \
    s16x8 af[4], bfr[2][2]; \
    _Pragma("unroll") \
    for (int i_ = 0; i_ < 4; ++i_) \
        af[i_] = *(const s16x8*)&As[P][wm * 64 + i_ * 16 + fr][pS]; \
    _Pragma("unroll") \
    for (int g_ = 0; g_ < 2; ++g_) \
        _Pragma("unroll") \
        for (int j_ = 0; j_ < 2; ++j_) \
            bfr[g_][j_] = *(const s16x8*)&Bs[P][g_ * 64 + wn * 32 + j_ * 16 + fr][pS]; \
    _Pragma("unroll") \
    for (int g_ = 0; g_ < 2; ++g_) \
        _Pragma("unroll") \
        for (int i_ = 0; i_ < 4; ++i_) \
            _Pragma("unroll") \
            for (int j_ = 0; j_ < 2; ++j_) \
                acc[g_][i_][j_] = __builtin_amdgcn_mfma_f32_16x16x32_bf16( \
                    af[i_], bfr[g_][j_], acc[g_][i_][j_], 0, 0, 0); \
} while(0)

__global__ __launch_bounds__(256, 3) void gate_gemm(
    const unsigned short* __restrict__ xb, const float* __restrict__ gw,
    const int* __restrict__ cursor,
    const int* __restrict__ tok_slot, const float* __restrict__ w_slot,
    unsigned short* __restrict__ act)
{
    const int e = blockIdx.z;
    const int n = cursor[e];
    const int row0 = blockIdx.y * BM;
    if (row0 >= n) return;
    const int b0 = e * NTOK;
    const int h0 = blockIdx.x * BH;

    __shared__ unsigned short As[2][BM][BK];
    __shared__ unsigned short Bs[2][BM][BK];   // rows = g*64 + hh
    __shared__ int toks[BM];
    __shared__ float swv[BM];

    const int tid = threadIdx.x;
    if (tid < BM) {
        int r = row0 + tid;
        toks[tid] = (r < n) ? tok_slot[b0 + r] : 0;
        swv[tid]  = (r < n) ? w_slot[b0 + r] : 0.f;
    }
    __syncthreads();

    const int lane = tid & 63;
    const int wid  = tid >> 6;
    const int wm = wid & 1;
    const int wn = wid >> 1;

    const int drow = lane >> 2;
    const int c8  = (((lane & 3) - ((lane >> 3) & 3)) & 3) * 8;   // swizzled src col
    const int arow = wid * 32 + drow;                              // LDS dest row
    const int acol = (lane & 3) * 8;                               // LDS dest col
    const unsigned short* asrc0 = xb + (size_t)toks[arow] * ND + c8;
    const unsigned short* asrc1 = xb + (size_t)toks[arow + 16] * ND + c8;
    const int br1 = arow + 16;
    const float* bsrc0 = gw + (((size_t)e * 2 + (arow >> 6)) * NH + h0 + (arow & 63)) * ND + c8;
    const float* bsrc1 = gw + (((size_t)e * 2 + (br1 >> 6)) * NH + h0 + (br1 & 63)) * ND + c8;

    f32x4 acc[2][4][2];
#pragma unroll
    for (int gg = 0; gg < 2; ++gg)
#pragma unroll
        for (int i = 0; i < 4; ++i)
#pragma unroll
            for (int j = 0; j < 2; ++j)
                acc[gg][i][j] = (f32x4){0.f, 0.f, 0.f, 0.f};

    const int fr = lane & 15;
    const int pS = (((lane >> 4) + (fr >> 1)) & 3) * 8;

    const int NT = ND / BK;   // 32 (even)

    // two named stage sets: X = even tiles, Y = odd tiles (static reg indexing)
    s16x8 xa0, xa1, ya0, ya1;
    f32x4 xb0, xb1, xb2, xb3, yb0, yb1, yb2, yb3;

    // prologue: issue tiles 0,1; write tile 0 into buf0
    G_ISSUE(xa0, xa1, xb0, xb1, xb2, xb3, 0);
    G_ISSUE(ya0, ya1, yb0, yb1, yb2, yb3, BK);
    SBAR();
    G_WRITE(0, xa0, xa1, xb0, xb1, xb2, xb3);
    __syncthreads();

    for (int t = 0; t < NT; t += 2) {
        // even iter: compute tile t from buf0; tile t+1 in Y regs; prefetch t+2 into X
        if (t + 2 < NT) G_ISSUE(xa0, xa1, xb0, xb1, xb2, xb3, (t + 2) * BK);
        SBAR();
        G_COMPUTE(0);
        SBAR();
        G_WRITE(1, ya0, ya1, yb0, yb1, yb2, yb3);   // tile t+1 -> buf1 (vmcnt(6) wait)
        __syncthreads();
        // odd iter: compute tile t+1 from buf1; prefetch t+3 into Y; write t+2 -> buf0
        if (t + 3 < NT) G_ISSUE(ya0, ya1, yb0, yb1, yb2, yb3, (t + 3) * BK);
        SBAR();
        G_COMPUTE(1);
        SBAR();
        if (t + 2 < NT) G_WRITE(0, xa0, xa1, xb0, xb1, xb2, xb3);
        __syncthreads();
    }

    const int rb = (lane >> 4) * 4;
#pragma unroll
    for (int i = 0; i < 4; ++i)
#pragma unroll
        for (int r = 0; r < 4; ++r) {
            int ml = wm * 64 + i * 16 + rb + r;
            int rr = row0 + ml;
            if (rr < n) {
                float w = swv[ml];
#pragma unroll
                for (int j = 0; j < 2; ++j) {
                    float g0v = acc[0][i][j][r];
                    float g1v = acc[1][i][j][r];
                    float u = 0.7978845608028654f * (g0v + 0.044715f * g0v * g0v * g0v);
                    float ex = __expf(2.f * u);
                    float th = 1.f - 2.f / (ex + 1.f);
                    float a = 0.5f * g0v * (1.f + th) * g1v * w;
                    act[(size_t)(b0 + rr) * NH + (h0 + wn * 32 + j * 16 + fr)] = f2bf(a);
                }
            }
        }
}

// ---------------- down GEMM: reg-staged 2-deep pipeline, pinned, partial output ------
#define DBM 128
#define DBN 128
#define DBK 32
#define KSPLIT 2
#define KC (NH / KSPLIT)

#define D_ISSUE(Sa0,Sa1,Sb0,Sb1,k) do { \
    Sa0 = *(const s16x8*)(asrc0 + (k)); \
    Sa1 = *(const s16x8*)(asrc1 + (k)); \
    Sb0 = *(const s16x8*)(bsrc0 + (k)); \
    Sb1 = *(const s16x8*)(bsrc1 + (k)); \
} while(0)

#define D_WRITE(P,Sa0,Sa1,Sb0,Sb1) do { \
    *(s16x8*)&As[P][arow][acol]      = Sa0; \
    *(s16x8*)&As[P][arow + 16][acol] = Sa1; \
    *(s16x8*)&Bs[P][arow][acol]      = Sb0; \
    *(s16x8*)&Bs[P][arow + 16][acol] = Sb1; \
} while(0)

#define D_COMPUTE(P) do { \
    s16x8 af[4], bfr[4]; \
    _Pragma("unroll") \
    for (int i_ = 0; i_ < 4; ++i_) \
        af[i_] = *(const s16x8*)&As[P][wm * 64 + i_ * 16 + fr][pS]; \
    _Pragma("unroll") \
    for (int j_ = 0; j_ < 4; ++j_) \
        bfr[j_] = *(const s16x8*)&Bs[P][wn * 64 + j_ * 16 + fr][pS]; \
    _Pragma("unroll") \
    for (int i_ = 0; i_ < 4; ++i_) \
        _Pragma("unroll") \
        for (int j_ = 0; j_ < 4; ++j_) \
            acc[i_][j_] = __builtin_amdgcn_mfma_f32_16x16x32_bf16( \
                af[i_], bfr[j_], acc[i_][j_], 0, 0, 0); \
} while(0)

__global__ __launch_bounds__(256, 3) void down_gemm(
    const unsigned short* __restrict__ act, const unsigned short* __restrict__ lwT,
    const int* __restrict__ cursor,
    const int* __restrict__ tok_slot, float* __restrict__ partial)
{
    const int e  = blockIdx.z >> 1;
    const int kc = blockIdx.z & 1;
    const int n = cursor[e];
    const int row0 = blockIdx.y * DBM;
    if (row0 >= n) return;
    const int b0 = e * NTOK;
    const int d0 = blockIdx.x * DBN;

    __shared__ unsigned short As[2][DBM][DBK];
    __shared__ unsigned short Bs[2][DBN][DBK];

    const int tid = threadIdx.x;
    const int lane = tid & 63;
    const int wid  = tid >> 6;
    const int wm = wid & 1;
    const int wn = wid >> 1;

    const int drow = lane >> 2;
    const int c8  = (((lane & 3) - ((lane >> 3) & 3)) & 3) * 8;
    const int arow = wid * 32 + drow;
    const int acol = (lane & 3) * 8;
    const int rr0 = row0 + arow, rr1 = rr0 + 16;
    const int sl0 = b0 + (rr0 < n ? rr0 : 0);
    const int sl1 = b0 + (rr1 < n ? rr1 : 0);
    const unsigned short* asrc0 = act + (size_t)sl0 * NH + kc * KC + c8;
    const unsigned short* asrc1 = act + (size_t)sl1 * NH + kc * KC + c8;
    const unsigned short* bsrc0 = lwT + ((size_t)e * ND + d0 + arow) * NH + kc * KC + c8;
    const unsigned short* bsrc1 = bsrc0 + 16 * NH;

    f32x4 acc[4][4];
#pragma unroll
    for (int i = 0; i < 4; ++i)
#pragma unroll
        for (int j = 0; j < 4; ++j)
            acc[i][j] = (f32x4){0.f, 0.f, 0.f, 0.f};

    const int fr = lane & 15;
    const int pS = (((lane >> 4) + (fr >> 1)) & 3) * 8;

    const int NT = KC / DBK;   // 32 (even)

    s16x8 xa0, xa1, xb0, xb1;   // even tiles
    s16x8 ya0, ya1, yb0, yb1;   // odd tiles

    D_ISSUE(xa0, xa1, xb0, xb1, 0);
    D_ISSUE(ya0, ya1, yb0, yb1, DBK);
    SBAR();
    D_WRITE(0, xa0, xa1, xb0, xb1);
    __syncthreads();

    for (int t = 0; t < NT; t += 2) {
        if (t + 2 < NT) D_ISSUE(xa0, xa1, xb0, xb1, (t + 2) * DBK);
        SBAR();
        D_COMPUTE(0);
        SBAR();
        D_WRITE(1, ya0, ya1, yb0, yb1);
        __syncthreads();
        if (t + 3 < NT) D_ISSUE(ya0, ya1, yb0, yb1, (t + 3) * DBK);
        SBAR();
        D_COMPUTE(1);
        SBAR();
        if (t + 2 < NT) D_WRITE(0, xa0, xa1, xb0, xb1);
        __syncthreads();
    }

    // non-atomic: write per-slot partial plane [kc][slot][d]
    float* prt = partial + ((size_t)kc * (NE * NTOK)) * ND;
    const int rb = (lane >> 4) * 4;
#pragma unroll
    for (int i = 0; i < 4; ++i)
#pragma unroll
        for (int r = 0; r < 4; ++r) {
            int ml = wm * 64 + i * 16 + rb + r;
            int rr = row0 + ml;
            if (rr < n) {
#pragma unroll
                for (int j = 0; j < 4; ++j)
                    prt[(size_t)(b0 + rr) * ND + d0 + wn * 64 + j * 16 + fr] = acc[i][j][r];
            }
        }
}

// ---------------- gather: out[t] = sum of 4 partial rows (2 slots x 2 kc) ------------
__global__ __launch_bounds__(256) void gather_out(const float* __restrict__ partial,
                                                  const int2* __restrict__ t2s,
                                                  float* __restrict__ out)
{
    const int t = blockIdx.x;
    const int2 ss = t2s[t];
    const size_t plane = (size_t)(NE * NTOK) * ND;
    const float* p00 = partial + (size_t)ss.x * ND;
    const float* p01 = p00 + plane;
    const float* p10 = partial + (size_t)ss.y * ND;
    const float* p11 = p10 + plane;
    const int d = threadIdx.x * 4;
    f32x4 a = *(const f32x4*)(p00 + d);
    f32x4 b = *(const f32x4*)(p01 + d);
    f32x4 c = *(const f32x4*)(p10 + d);
    f32x4 e = *(const f32x4*)(p11 + d);
    f32x4 v = a + b + c + e;
    *(f32x4*)(out + (size_t)t * ND + d) = v;
}

extern "C" void kernel_launch(void* const* d_in, const int* in_sizes, int n_in,
                              void* d_out, int out_size, void* d_ws, size_t ws_size,
                              hipStream_t stream)
{
    const float* x      = (const float*)d_in[0];
    const float* rscale = (const float*)d_in[1];
    const float* rw     = (const float*)d_in[2];
    const float* gw     = (const float*)d_in[3];
    const float* lw     = (const float*)d_in[4];
    const float* pes    = (const float*)d_in[5];
    float* out = (float*)d_out;

    // workspace layout (bytes):
    //   0          cursor[8] (zeroed, doubles as counts)
    //   128        tok_slot[8][2048] int        65536
    //   65664      w_slot[8][2048] f32          65536
    //   131200     t2s[2048] int2               16384
    //   147584     xb  bf16 [2048][1024]        4194304   -> 4341888
    //   4341888    act bf16 [8*2048][2048]      67108864  -> 71450752
    //   71450752   lwT bf16 [8][1024][2048]     33554432  -> 105005184
    //   105005184  partial f32 [2][8*2048][1024] 134217728 -> ~229 MB
    char* ws = (char*)d_ws;
    int* cursor = (int*)ws;
    int*   tok_slot      = (int*)(ws + 128);
    float* w_slot        = (float*)(ws + 65664);
    int2*  t2s           = (int2*)(ws + 131200);
    unsigned short* xb   = (unsigned short*)(ws + 147584);
    unsigned short* act  = (unsigned short*)(ws + 4341888);
    unsigned short* lwT  = (unsigned short*)(ws + 71450752);
    float* partial       = (float*)(ws + 105005184);

    hipMemsetAsync(d_ws, 0, 128, stream);

    router_kernel<<<NTOK / 4, 256, 0, stream>>>(x, rscale, rw, pes, cursor,
                                                tok_slot, w_slot, t2s, xb);

    prep_weights<<<TL_BLOCKS, 256, 0, stream>>>(lw, lwT);

    dim3 g2(NH / BH, NTOK / BM, NE);   // 32 x 16 x 8, early-exit
    gate_gemm<<<g2, 256, 0, stream>>>(xb, gw, cursor, tok_slot, w_slot, act);

    dim3 g3(ND / DBN, NTOK / DBM, NE * KSPLIT); // 8 x 16 x 16
    down_gemm<<<g3, 256, 0, stream>>>(act, lwT, cursor, tok_slot, partial);

    gather_out<<<NTOK, 256, 0, stream>>>(partial, t2s, out);
}

// Round 5
// 401.233 us; speedup vs baseline: 1.0816x; 1.0058x over previous
//
#include <hip/hip_runtime.h>
#include <math.h>

#define NB 2
#define NL 1024
#define ND 1024
#define NH 2048
#define NE 8
#define NTOK (NB*NL)      // 2048 tokens; per-expert slot capacity = NTOK
#define NSLOT (NTOK*2)

typedef float f32x4 __attribute__((ext_vector_type(4)));
typedef short s16x8 __attribute__((ext_vector_type(8)));
typedef short s16x4 __attribute__((ext_vector_type(4)));
typedef unsigned u32x4 __attribute__((ext_vector_type(4)));

__device__ __forceinline__ unsigned short f2bf(float f) {
    union { float f; unsigned u; } v; v.f = f;
    unsigned r = v.u + 0x7FFFu + ((v.u >> 16) & 1u);
    return (unsigned short)(r >> 16);
}

// packed fp32->bf16 RNE convert; VOLATILE so it cannot be hoisted above the
// volatile s_waitcnt that guarantees its inputs (rule #18: register-only ops
// are not ordered by "memory" clobbers).
__device__ __forceinline__ unsigned pk2v(float a, float b) {
    unsigned r;
    asm volatile("v_cvt_pk_bf16_f32 %0, %1, %2" : "=v"(r) : "v"(a), "v"(b));
    return r;
}

// un-sinkable global load: inline asm cannot be moved past other volatile asm
// nor rematerialized at the use site (the round-3/4 failure mode).
__device__ __forceinline__ void gld4(f32x4& d, const float* p) {
    asm volatile("global_load_dwordx4 %0, %1, off" : "=&v"(d) : "v"(p));
}

// async global->LDS DMA, 16B per lane; LDS dest = uniform base + lane*16
__device__ __forceinline__ void gl_lds16(const unsigned short* g, unsigned short* l) {
    __builtin_amdgcn_global_load_lds(
        (const __attribute__((address_space(1))) unsigned int*)(const void*)g,
        (__attribute__((address_space(3))) unsigned int*)(void*)l, 16, 0, 0);
}

#define SBAR() __builtin_amdgcn_sched_barrier(0)
// counted vmem drain + scheduling fence
#define VMW(N) do { asm volatile("s_waitcnt vmcnt(" #N ")" ::: "memory"); SBAR(); } while(0)
// raw barrier with LDS-write flush (for kernels that ds_write)
#define WAVE_SYNC() do { \
    asm volatile("s_waitcnt lgkmcnt(0)" ::: "memory"); \
    __builtin_amdgcn_s_barrier(); SBAR(); } while(0)
// raw barrier (no ds_writes to flush)
#define BAR() do { __builtin_amdgcn_s_barrier(); SBAR(); } while(0)

// ---------------- Router: RMSNorm + logits + top2 + scatter + x->bf16 ----------------
// one wave per token; 4 waves per block
__global__ void router_kernel(const float* __restrict__ x,
                              const float* __restrict__ rscale,
                              const float* __restrict__ rw,
                              const float* __restrict__ pes,
                              int* __restrict__ cursor,
                              int* __restrict__ tok_slot,
                              float* __restrict__ w_slot,
                              int2* __restrict__ t2s,
                              unsigned short* __restrict__ xb)
{
    const int wave = threadIdx.x >> 6;
    const int lane = threadIdx.x & 63;
    const int t = blockIdx.x * 4 + wave;
    const float* xt = x + (size_t)t * ND;
    unsigned short* xbt = xb + (size_t)t * ND;

    float part[NE];
#pragma unroll
    for (int e = 0; e < NE; ++e) part[e] = 0.f;
    float ss = 0.f;

#pragma unroll
    for (int i = 0; i < 4; ++i) {
        int d = (lane + 64 * i) * 4;
        float4 xv = *(const float4*)(xt + d);
        float4 sv = *(const float4*)(rscale + d);
        // side-effect: write bf16 copy of x
        s16x4 o;
        o[0] = (short)f2bf(xv.x); o[1] = (short)f2bf(xv.y);
        o[2] = (short)f2bf(xv.z); o[3] = (short)f2bf(xv.w);
        *(s16x4*)(xbt + d) = o;
        float xs[4] = {xv.x, xv.y, xv.z, xv.w};
        float sc[4] = {sv.x, sv.y, sv.z, sv.w};
        const float* rwp = rw + (size_t)d * NE;
#pragma unroll
        for (int c = 0; c < 4; ++c) {
            float v = xs[c];
            ss += v * v;
            float xr = v * sc[c];
            float4 r0 = *(const float4*)(rwp + c * NE);
            float4 r1 = *(const float4*)(rwp + c * NE + 4);
            part[0] += xr * r0.x; part[1] += xr * r0.y;
            part[2] += xr * r0.z; part[3] += xr * r0.w;
            part[4] += xr * r1.x; part[5] += xr * r1.y;
            part[6] += xr * r1.z; part[7] += xr * r1.w;
        }
    }
#pragma unroll
    for (int off = 32; off > 0; off >>= 1) {
        ss += __shfl_xor(ss, off, 64);
#pragma unroll
        for (int e = 0; e < NE; ++e) part[e] += __shfl_xor(part[e], off, 64);
    }
    if (lane == 0) {
        float rinv = rsqrtf(ss * (1.f / ND) + 1e-6f) * rsqrtf((float)ND);
        float lg[NE];
#pragma unroll
        for (int e = 0; e < NE; ++e) lg[e] = part[e] * rinv;
        int i0 = 0; float b0 = lg[0];
#pragma unroll
        for (int e = 1; e < NE; ++e) if (lg[e] > b0) { b0 = lg[e]; i0 = e; }
        int i1 = -1; float b1 = -INFINITY;
#pragma unroll
        for (int e = 0; e < NE; ++e) if (e != i0 && lg[e] > b1) { b1 = lg[e]; i1 = e; }
        float e1 = expf(b1 - b0);
        float denom = 1.f + e1;
        float w0 = pes[i0] / denom;
        float w1 = pes[i1] * e1 / denom;
        int s0 = atomicAdd(&cursor[i0], 1);
        tok_slot[i0 * NTOK + s0] = t; w_slot[i0 * NTOK + s0] = w0;
        int s1 = atomicAdd(&cursor[i1], 1);
        tok_slot[i1 * NTOK + s1] = t; w_slot[i1 * NTOK + s1] = w1;
        t2s[t] = make_int2(i0 * NTOK + s0, i1 * NTOK + s1);
    }
}

// ---------------- prep_weights: lw [E][H][D] fp32 -> lwT bf16 [E][D][H] only ----------
#define TL_BLOCKS ((ND/64)*(NH/64)*NE)       // 4096
__global__ __launch_bounds__(256) void prep_weights(const float* __restrict__ lw,
                                                    unsigned short* __restrict__ lwT)
{
    const int b2 = blockIdx.x;
    const int tid = threadIdx.x;
    const int d0 = (b2 & 15) * 64;
    const int h0 = ((b2 >> 4) & 31) * 64;
    const int e  = b2 >> 9;
    __shared__ unsigned short T[64][66];
    {
        const int hr = tid >> 2;
        const int dc = (tid & 3) * 16;
        const float* p = lw + ((size_t)e * NH + h0 + hr) * ND + d0 + dc;
        float t[16];
        *(float4*)&t[0]  = *(const float4*)(p);
        *(float4*)&t[4]  = *(const float4*)(p + 4);
        *(float4*)&t[8]  = *(const float4*)(p + 8);
        *(float4*)&t[12] = *(const float4*)(p + 12);
#pragma unroll
        for (int i = 0; i < 8; ++i) {
            unsigned pk = (unsigned)f2bf(t[2 * i]) | ((unsigned)f2bf(t[2 * i + 1]) << 16);
            *(unsigned*)&T[hr][dc + 2 * i] = pk;
        }
    }
    __syncthreads();
    {
        const int dr = tid >> 2;
        const int hc = (tid & 3) * 16;
        s16x8 o0, o1;
#pragma unroll
        for (int i = 0; i < 8; ++i) o0[i] = (short)T[hc + i][dr];
#pragma unroll
        for (int i = 0; i < 8; ++i) o1[i] = (short)T[hc + 8 + i][dr];
        unsigned short* q = lwT + ((size_t)e * ND + d0 + dr) * NH + h0 + hc;
        *(s16x8*)(q)     = o0;
        *(s16x8*)(q + 8) = o1;
    }
}

// ---------------- gate GEMM: asm-pinned 2-deep pipeline, counted vmcnt ---------------
// A (bf16) via global_load_lds 1 tile ahead (xb is L2-hot).
// B (fp32) via asm global_load_dwordx4 2 tiles ahead into forced-live registers,
// converted to bf16 at LDS-write time. Raw s_barrier + counted vmcnt(4): the
// next-next B tile's 4 loads stay in flight across every barrier.
#define BM 128
#define BH 64
#define BK 32

#define G_WRITE(P,B0,B1,B2,B3) do { \
    u32x4 w0_, w1_; \
    w0_[0] = pk2v(B0[0],B0[1]); w0_[1] = pk2v(B0[2],B0[3]); \
    w0_[2] = pk2v(B1[0],B1[1]); w0_[3] = pk2v(B1[2],B1[3]); \
    w1_[0] = pk2v(B2[0],B2[1]); w1_[1] = pk2v(B2[2],B2[3]); \
    w1_[2] = pk2v(B3[0],B3[1]); w1_[3] = pk2v(B3[2],B3[3]); \
    *(u32x4*)&Bs[P][arow][acol]      = w0_; \
    *(u32x4*)&Bs[P][arow + 16][acol] = w1_; \
} while(0)

#define G_COMPUTE(P) do { \
    s16x8 af[4], bfr[2][2]; \
    _Pragma("unroll") \
    for (int i_ = 0; i_ < 4; ++i_) \
        af[i_] = *(const s16x8*)&As[P][wm * 64 + i_ * 16 + fr][pS]; \
    _Pragma("unroll") \
    for (int g_ = 0; g_ < 2; ++g_) \
        _Pragma("unroll") \
        for (int j_ = 0; j_ < 2; ++j_) \
            bfr[g_][j_] = *(const s16x8*)&Bs[P][g_ * 64 + wn * 32 + j_ * 16 + fr][pS]; \
    _Pragma("unroll") \
    for (int g_ = 0; g_ < 2; ++g_) \
        _Pragma("unroll") \
        for (int i_ = 0; i_ < 4; ++i_) \
            _Pragma("unroll") \
            for (int j_ = 0; j_ < 2; ++j_) \
                acc[g_][i_][j_] = __builtin_amdgcn_mfma_f32_16x16x32_bf16( \
                    af[i_], bfr[g_][j_], acc[g_][i_][j_], 0, 0, 0); \
} while(0)

#define GLD_B(B0,B1,B2,B3,k) do { \
    gld4(B0, bsrc0 + (k)); gld4(B1, bsrc0 + (k) + 4); \
    gld4(B2, bsrc1 + (k)); gld4(B3, bsrc1 + (k) + 4); \
} while(0)

__global__ __launch_bounds__(256, 3) void gate_gemm(
    const unsigned short* __restrict__ xb, const float* __restrict__ gw,
    const int* __restrict__ cursor,
    const int* __restrict__ tok_slot, const float* __restrict__ w_slot,
    unsigned short* __restrict__ act)
{
    const int e = blockIdx.z;
    const int n = cursor[e];
    const int row0 = blockIdx.y * BM;
    if (row0 >= n) return;
    const int b0 = e * NTOK;
    const int h0 = blockIdx.x * BH;

    __shared__ unsigned short As[2][BM][BK];
    __shared__ unsigned short Bs[2][BM][BK];   // rows = g*64 + hh
    __shared__ int toks[BM];
    __shared__ float swv[BM];

    const int tid = threadIdx.x;
    if (tid < BM) {
        int r = row0 + tid;
        toks[tid] = (r < n) ? tok_slot[b0 + r] : 0;
        swv[tid]  = (r < n) ? w_slot[b0 + r] : 0.f;
    }
    __syncthreads();

    const int lane = tid & 63;
    const int wid  = tid >> 6;
    const int wm = wid & 1;
    const int wn = wid >> 1;

    const int drow = lane >> 2;
    const int c8  = (((lane & 3) - ((lane >> 3) & 3)) & 3) * 8;   // swizzled src col
    const int arow = wid * 32 + drow;                              // LDS dest row
    const int acol = (lane & 3) * 8;                               // LDS dest col
    const unsigned short* asrc0 = xb + (size_t)toks[arow] * ND + c8;
    const unsigned short* asrc1 = xb + (size_t)toks[arow + 16] * ND + c8;
    const int br1 = arow + 16;
    const float* bsrc0 = gw + (((size_t)e * 2 + (arow >> 6)) * NH + h0 + (arow & 63)) * ND + c8;
    const float* bsrc1 = gw + (((size_t)e * 2 + (br1 >> 6)) * NH + h0 + (br1 & 63)) * ND + c8;

    f32x4 acc[2][4][2];
#pragma unroll
    for (int gg = 0; gg < 2; ++gg)
#pragma unroll
        for (int i = 0; i < 4; ++i)
#pragma unroll
            for (int j = 0; j < 2; ++j)
                acc[gg][i][j] = (f32x4){0.f, 0.f, 0.f, 0.f};

    const int fr = lane & 15;
    const int pS = (((lane >> 4) + (fr >> 1)) & 3) * 8;

    const int NT = ND / BK;   // 32 (even)

    f32x4 Xb0, Xb1, Xb2, Xb3;   // even-tile B stage (asm outputs: forced live)
    f32x4 Yb0, Yb1, Yb2, Yb3;   // odd-tile B stage

    // prologue: A(0) dma -> buf0; B(0)->X; B(1)->Y; drain A(0)+B(0), keep B(1) in flight
    gl_lds16(asrc0, &As[0][wid * 32][0]);
    gl_lds16(asrc1, &As[0][wid * 32 + 16][0]);
    SBAR();
    GLD_B(Xb0, Xb1, Xb2, Xb3, 0);
    GLD_B(Yb0, Yb1, Yb2, Yb3, BK);
    VMW(4);
    G_WRITE(0, Xb0, Xb1, Xb2, Xb3);
    WAVE_SYNC();

    for (int t = 0; t < NT; t += 2) {
        // ---- even tile t (buf0); Y holds B(t+1) in flight; X free ----
        if (t + 1 < NT) {
            gl_lds16(asrc0 + (t + 1) * BK, &As[1][wid * 32][0]);
            gl_lds16(asrc1 + (t + 1) * BK, &As[1][wid * 32 + 16][0]);
        }
        SBAR();                       // pin issue order: A(t+1) older than B(t+2)
        if (t + 2 < NT) GLD_B(Xb0, Xb1, Xb2, Xb3, (t + 2) * BK);
        G_COMPUTE(0);
        // outstanding: B(t+1)[4] oldest, A(t+1)[2], B(t+2)[4] youngest
        if (t + 2 < NT) { VMW(4); } else { VMW(0); }
        if (t + 1 < NT) {
            G_WRITE(1, Yb0, Yb1, Yb2, Yb3);
            WAVE_SYNC();
            // ---- odd tile t+1 (buf1); X holds B(t+2) in flight ----
            if (t + 2 < NT) {
                gl_lds16(asrc0 + (t + 2) * BK, &As[0][wid * 32][0]);
                gl_lds16(asrc1 + (t + 2) * BK, &As[0][wid * 32 + 16][0]);
            }
            SBAR();
            if (t + 3 < NT) GLD_B(Yb0, Yb1, Yb2, Yb3, (t + 3) * BK);
            G_COMPUTE(1);
            if (t + 3 < NT) { VMW(4); } else if (t + 2 < NT) { VMW(0); }
            if (t + 2 < NT) {
                G_WRITE(0, Xb0, Xb1, Xb2, Xb3);
                WAVE_SYNC();
            }
        }
    }

    const int rb = (lane >> 4) * 4;
#pragma unroll
    for (int i = 0; i < 4; ++i)
#pragma unroll
        for (int r = 0; r < 4; ++r) {
            int ml = wm * 64 + i * 16 + rb + r;
            int rr = row0 + ml;
            if (rr < n) {
                float w = swv[ml];
#pragma unroll
                for (int j = 0; j < 2; ++j) {
                    float g0v = acc[0][i][j][r];
                    float g1v = acc[1][i][j][r];
                    float u = 0.7978845608028654f * (g0v + 0.044715f * g0v * g0v * g0v);
                    float ex = __expf(2.f * u);
                    float th = 1.f - 2.f / (ex + 1.f);
                    float a = 0.5f * g0v * (1.f + th) * g1v * w;
                    act[(size_t)(b0 + rr) * NH + (h0 + wn * 32 + j * 16 + fr)] = f2bf(a);
                }
            }
        }
}

// ---------------- down GEMM: gl_lds 2 tiles ahead, 3 LDS buffers, counted vmcnt ------
#define DBM 128
#define DBN 128
#define DBK 32
#define KSPLIT 2
#define KC (NH / KSPLIT)

#define D_STAGE(b, k) do { \
    gl_lds16(asrc0 + (k), &As[b][wid * 32][0]); \
    gl_lds16(asrc1 + (k), &As[b][wid * 32 + 16][0]); \
    gl_lds16(bsrc0 + (k), &Bs[b][wid * 32][0]); \
    gl_lds16(bsrc1 + (k), &Bs[b][wid * 32 + 16][0]); \
} while(0)

#define D_COMPUTE(P) do { \
    s16x8 af[4], bfr[4]; \
    _Pragma("unroll") \
    for (int i_ = 0; i_ < 4; ++i_) \
        af[i_] = *(const s16x8*)&As[P][wm * 64 + i_ * 16 + fr][pS]; \
    _Pragma("unroll") \
    for (int j_ = 0; j_ < 4; ++j_) \
        bfr[j_] = *(const s16x8*)&Bs[P][wn * 64 + j_ * 16 + fr][pS]; \
    _Pragma("unroll") \
    for (int i_ = 0; i_ < 4; ++i_) \
        _Pragma("unroll") \
        for (int j_ = 0; j_ < 4; ++j_) \
            acc[i_][j_] = __builtin_amdgcn_mfma_f32_16x16x32_bf16( \
                af[i_], bfr[j_], acc[i_][j_], 0, 0, 0); \
} while(0)

__global__ __launch_bounds__(256, 3) void down_gemm(
    const unsigned short* __restrict__ act, const unsigned short* __restrict__ lwT,
    const int* __restrict__ cursor,
    const int* __restrict__ tok_slot, float* __restrict__ partial)
{
    const int e  = blockIdx.z >> 1;
    const int kc = blockIdx.z & 1;
    const int n = cursor[e];
    const int row0 = blockIdx.y * DBM;
    if (row0 >= n) return;
    const int b0 = e * NTOK;
    const int d0 = blockIdx.x * DBN;

    __shared__ unsigned short As[3][DBM][DBK];
    __shared__ unsigned short Bs[3][DBM][DBK];
    __shared__ int stok[DBM];

    const int tid = threadIdx.x;
    if (tid < DBM) {
        int r = row0 + tid;
        stok[tid] = (r < n) ? tok_slot[b0 + r] : 0;
    }
    __syncthreads();

    const int lane = tid & 63;
    const int wid  = tid >> 6;
    const int wm = wid & 1;
    const int wn = wid >> 1;

    const int drow = lane >> 2;
    const int c8  = (((lane & 3) - ((lane >> 3) & 3)) & 3) * 8;
    const int arow = wid * 32 + drow;
    const int rr0 = row0 + arow, rr1 = rr0 + 16;
    const int sl0 = b0 + (rr0 < n ? rr0 : 0);
    const int sl1 = b0 + (rr1 < n ? rr1 : 0);
    const unsigned short* asrc0 = act + (size_t)sl0 * NH + kc * KC + c8;
    const unsigned short* asrc1 = act + (size_t)sl1 * NH + kc * KC + c8;
    const unsigned short* bsrc0 = lwT + ((size_t)e * ND + d0 + arow) * NH + kc * KC + c8;
    const unsigned short* bsrc1 = bsrc0 + 16 * NH;

    f32x4 acc[4][4];
#pragma unroll
    for (int i = 0; i < 4; ++i)
#pragma unroll
        for (int j = 0; j < 4; ++j)
            acc[i][j] = (f32x4){0.f, 0.f, 0.f, 0.f};

    const int fr = lane & 15;
    const int pS = (((lane >> 4) + (fr >> 1)) & 3) * 8;

    const int NT = KC / DBK;   // 32

    // prologue: stage tiles 0,1; drain tile 0 only (tile 1 stays in flight)
    D_STAGE(0, 0);
    SBAR();
    D_STAGE(1, DBK);
    VMW(4);
    BAR();

    int bc = 0;
    for (int t = 0; t < NT; ++t) {
        int b2 = bc + 2; if (b2 >= 3) b2 -= 3;
        if (t + 2 < NT) D_STAGE(b2, (t + 2) * DBK);
        SBAR();
        D_COMPUTE(bc);
        // outstanding: tile(t+1)[4] oldest, tile(t+2)[4] youngest
        if (t + 2 < NT) { VMW(4); }
        else if (t + 1 < NT) { VMW(0); }
        if (t + 1 < NT) BAR();
        bc += 1; if (bc == 3) bc = 0;
    }

    // non-atomic: write per-slot partial plane [kc][slot][d]
    float* prt = partial + ((size_t)kc * (NE * NTOK)) * ND;
    const int rb = (lane >> 4) * 4;
#pragma unroll
    for (int i = 0; i < 4; ++i)
#pragma unroll
        for (int r = 0; r < 4; ++r) {
            int ml = wm * 64 + i * 16 + rb + r;
            int rr = row0 + ml;
            if (rr < n) {
#pragma unroll
                for (int j = 0; j < 4; ++j)
                    prt[(size_t)(b0 + rr) * ND + d0 + wn * 64 + j * 16 + fr] = acc[i][j][r];
            }
        }
}

// ---------------- gather: out[t] = sum of 4 partial rows (2 slots x 2 kc) ------------
__global__ __launch_bounds__(256) void gather_out(const float* __restrict__ partial,
                                                  const int2* __restrict__ t2s,
                                                  float* __restrict__ out)
{
    const int t = blockIdx.x;
    const int2 ss = t2s[t];
    const size_t plane = (size_t)(NE * NTOK) * ND;
    const float* p00 = partial + (size_t)ss.x * ND;
    const float* p01 = p00 + plane;
    const float* p10 = partial + (size_t)ss.y * ND;
    const float* p11 = p10 + plane;
    const int d = threadIdx.x * 4;
    f32x4 a = *(const f32x4*)(p00 + d);
    f32x4 b = *(const f32x4*)(p01 + d);
    f32x4 c = *(const f32x4*)(p10 + d);
    f32x4 e = *(const f32x4*)(p11 + d);
    f32x4 v = a + b + c + e;
    *(f32x4*)(out + (size_t)t * ND + d) = v;
}

extern "C" void kernel_launch(void* const* d_in, const int* in_sizes, int n_in,
                              void* d_out, int out_size, void* d_ws, size_t ws_size,
                              hipStream_t stream)
{
    const float* x      = (const float*)d_in[0];
    const float* rscale = (const float*)d_in[1];
    const float* rw     = (const float*)d_in[2];
    const float* gw     = (const float*)d_in[3];
    const float* lw     = (const float*)d_in[4];
    const float* pes    = (const float*)d_in[5];
    float* out = (float*)d_out;

    // workspace layout (bytes):
    //   0          cursor[8] (zeroed, doubles as counts)
    //   128        tok_slot[8][2048] int        65536
    //   65664      w_slot[8][2048] f32          65536
    //   131200     t2s[2048] int2               16384
    //   147584     xb  bf16 [2048][1024]        4194304   -> 4341888
    //   4341888    act bf16 [8*2048][2048]      67108864  -> 71450752
    //   71450752   lwT bf16 [8][1024][2048]     33554432  -> 105005184
    //   105005184  partial f32 [2][8*2048][1024] 134217728 -> ~229 MB
    char* ws = (char*)d_ws;
    int* cursor = (int*)ws;
    int*   tok_slot      = (int*)(ws + 128);
    float* w_slot        = (float*)(ws + 65664);
    int2*  t2s           = (int2*)(ws + 131200);
    unsigned short* xb   = (unsigned short*)(ws + 147584);
    unsigned short* act  = (unsigned short*)(ws + 4341888);
    unsigned short* lwT  = (unsigned short*)(ws + 71450752);
    float* partial       = (float*)(ws + 105005184);

    hipMemsetAsync(d_ws, 0, 128, stream);

    router_kernel<<<NTOK / 4, 256, 0, stream>>>(x, rscale, rw, pes, cursor,
                                                tok_slot, w_slot, t2s, xb);

    prep_weights<<<TL_BLOCKS, 256, 0, stream>>>(lw, lwT);

    dim3 g2(NH / BH, NTOK / BM, NE);   // 32 x 16 x 8, early-exit
    gate_gemm<<<g2, 256, 0, stream>>>(xb, gw, cursor, tok_slot, w_slot, act);

    dim3 g3(ND / DBN, NTOK / DBM, NE * KSPLIT); // 8 x 16 x 16
    down_gemm<<<g3, 256, 0, stream>>>(act, lwT, cursor, tok_slot, partial);

    gather_out<<<NTOK, 256, 0, stream>>>(partial, t2s, out);
}